// Round 2
// baseline (33216.904 us; speedup 1.0000x reference)
//
#include <hip/hip_runtime.h>
#include <cstdint>

#define NN 8192
#define DD 512
#define CC 4
#define TT 8
#define EE 32768
#define TE (TT*EE)

constexpr int FLAG_SILU = 1, FLAG_RES = 2;

__device__ __forceinline__ float silu_f(float x) { return x / (1.f + __expf(-x)); }

__device__ __forceinline__ float wave_sum(float v) {
#pragma unroll
  for (int off = 32; off; off >>= 1) v += __shfl_xor(v, off);
  return v;
}

// ---------------- gather functors (row index is chunk-local) ----------------
struct AgDirect { const float* p; int K;
  __device__ float operator()(int m, int k) const { return p[(size_t)m * K + k]; } };

struct AgFeat { const float* h; const float* radial_t; const float* ea_t;
                const int* row_t; const int* col_t;
  __device__ float operator()(int e, int k) const {
    if (k < 512)  return h[((size_t)row_t[e] << 9) + k];
    if (k < 1024) return h[((size_t)col_t[e] << 9) + (k - 512)];
    if (k < 1040) return radial_t[((size_t)e << 4) + (k - 1024)];
    return ea_t[e]; } };

struct AgEf { const float* hn; const float* ea_t; const int* row_t; const int* col_t;
  __device__ float operator()(int e, int k) const {
    if (k < 512)  return hn[((size_t)row_t[e] << 9) + k];
    if (k == 512) return ea_t[e];
    return hn[((size_t)col_t[e] << 9) + (k - 513)]; } };

struct AgHcat { const float* h; const float* agg;
  __device__ float operator()(int m, int k) const {
    return (k < 512) ? h[((size_t)m << 9) + k] : agg[((size_t)m << 9) + (k - 512)]; } };

// ------- generic tiled GEMM: out[m][o] = act( A[m,:] . W[o,:] + b[o] ) (+res), O=512 -------
template<class AG>
__global__ __launch_bounds__(256)
void gemm_k(AG ag, const float* __restrict__ w, const float* __restrict__ bias,
            const float* __restrict__ res, float* __restrict__ out,
            int K, int flags)
{
  __shared__ __align__(16) float As[16][128];
  __shared__ __align__(16) float Ws[16][128];
  const int m0 = blockIdx.x * 128, o0 = blockIdx.y * 128;
  const int tid = threadIdx.x;
  const int tm = tid & 15, to = tid >> 4;

  float acc[8][8];
#pragma unroll
  for (int x = 0; x < 8; ++x)
#pragma unroll
    for (int y = 0; y < 8; ++y) acc[x][y] = 0.f;

  for (int k0 = 0; k0 < K; k0 += 16) {
#pragma unroll
    for (int i = 0; i < 8; ++i) {
      int idx = tid + i * 256;
      int kk = idx >> 7, r = idx & 127;
      int k = k0 + kk;
      As[kk][r] = (k < K) ? ag(m0 + r, k) : 0.f;
    }
#pragma unroll
    for (int i = 0; i < 8; ++i) {
      int idx = tid + i * 256;
      int kk = idx >> 7, r = idx & 127;
      int k = k0 + kk;
      Ws[kk][r] = (k < K) ? w[(size_t)(o0 + r) * K + k] : 0.f;
    }
    __syncthreads();
#pragma unroll
    for (int kk = 0; kk < 16; ++kk) {
      float a[8], b[8];
      *(float4*)&a[0] = *(const float4*)&As[kk][tm * 4];
      *(float4*)&a[4] = *(const float4*)&As[kk][64 + tm * 4];
      *(float4*)&b[0] = *(const float4*)&Ws[kk][to * 4];
      *(float4*)&b[4] = *(const float4*)&Ws[kk][64 + to * 4];
#pragma unroll
      for (int x = 0; x < 8; ++x)
#pragma unroll
        for (int y = 0; y < 8; ++y) acc[x][y] += a[x] * b[y];
    }
    __syncthreads();
  }

#pragma unroll
  for (int x = 0; x < 8; ++x) {
    int r = m0 + ((x < 4) ? (tm * 4 + x) : (64 + tm * 4 + x - 4));
#pragma unroll
    for (int y = 0; y < 8; ++y) {
      int c = o0 + ((y < 4) ? (to * 4 + y) : (64 + to * 4 + y - 4));
      float v = acc[x][y];
      if (bias) v += bias[c];
      if (flags & FLAG_SILU) v = silu_f(v);
      if (flags & FLAG_RES) v += res[(size_t)r * 512 + c];
      out[(size_t)r * 512 + c] = v;
    }
  }
}

// ---------------- cd / radial / per-(t,c,d) sq-sum partials ----------------
__global__ __launch_bounds__(256)
void cdrad_k(const float* __restrict__ coord, const int* __restrict__ eidx,
             float* __restrict__ cd, float* __restrict__ radial, float* __restrict__ nrm)
{
  int m = blockIdx.x * 256 + threadIdx.x;          // < TE
  int t = m >> 15, e = m & (EE - 1);
  int r = eidx[(t << 16) + e], c = eidx[(t << 16) + EE + e];
  float d[12];
#pragma unroll
  for (int i = 0; i < 12; ++i) d[i] = coord[r * 12 + i] - coord[c * 12 + i];
#pragma unroll
  for (int i = 0; i < 12; ++i) cd[(size_t)m * 12 + i] = d[i];
  float sq[16];
#pragma unroll
  for (int ci = 0; ci < 4; ++ci)
#pragma unroll
    for (int di = 0; di < 4; ++di) {
      float v = d[ci*3]*d[di*3] + d[ci*3+1]*d[di*3+1] + d[ci*3+2]*d[di*3+2];
      radial[(size_t)m * 16 + ci * 4 + di] = v;
      sq[ci * 4 + di] = v * v;
    }
#pragma unroll
  for (int i = 0; i < 16; ++i) sq[i] = wave_sum(sq[i]);
  if ((threadIdx.x & 63) == 0) {
#pragma unroll
    for (int i = 0; i < 16; ++i) atomicAdd(&nrm[t * 16 + i], sq[i]);
  }
}

__global__ __launch_bounds__(256)
void rnorm_k(float* __restrict__ radial, const float* __restrict__ nrm)
{
  int id = blockIdx.x * 256 + threadIdx.x;         // < TE*16
  int t = id >> 19, j = id & 15;
  radial[id] /= fmaxf(sqrtf(nrm[t * 16 + j]), 1e-12f);
}

// ---------------- segment sum of msg chunk into segt (N, 512) ----------------
__global__ __launch_bounds__(256)
void segsc_k(const float* __restrict__ msg, const int* __restrict__ row_t,
             float* __restrict__ segt)
{
  int id = blockIdx.x * 256 + threadIdx.x;         // < EE*128
  int e = id >> 7, part = (id & 127) << 2;
  int r = row_t[e];
  float4 v = *(const float4*)(msg + ((size_t)e << 9) + part);
  float* s = segt + ((size_t)r << 9) + part;
  atomicAdd(s + 0, v.x); atomicAdd(s + 1, v.y);
  atomicAdd(s + 2, v.z); atomicAdd(s + 3, v.w);
}

// ------ w[e,c] = hid[e,:] . cW2t[c,:]  (one wave per edge) ------
__global__ __launch_bounds__(256)
void wv_k(const float* __restrict__ hid, const float* __restrict__ cW2t, float* __restrict__ w)
{
  int gid = blockIdx.x * 256 + threadIdx.x;
  int wv = gid >> 6;                               // edge id < EE
  int lane = threadIdx.x & 63;
  const float4* hv = (const float4*)(hid + ((size_t)wv << 9));
  float4 h0 = hv[lane * 2], h1 = hv[lane * 2 + 1];
  float p[4];
#pragma unroll
  for (int c = 0; c < 4; ++c) {
    const float4* wp = (const float4*)(cW2t + ((size_t)c << 9));
    float4 w0 = wp[lane * 2], w1 = wp[lane * 2 + 1];
    p[c] = h0.x*w0.x + h0.y*w0.y + h0.z*w0.z + h0.w*w0.w
         + h1.x*w1.x + h1.y*w1.y + h1.z*w1.z + h1.w*w1.w;
  }
#pragma unroll
  for (int c = 0; c < 4; ++c) p[c] = wave_sum(p[c]);
  if (lane == 0) {
    float4 o; o.x = p[0]; o.y = p[1]; o.z = p[2]; o.w = p[3];
    *(float4*)(w + (size_t)wv * 4) = o;
  }
}

// ---------------- trans scatter: sumv += cd*w, cnt += 1 ----------------
__global__ __launch_bounds__(256)
void trsc_k(const float* __restrict__ cd_t, const float* __restrict__ w,
            const int* __restrict__ row_t, float* __restrict__ sumv, float* __restrict__ cnt)
{
  int e = blockIdx.x * 256 + threadIdx.x;          // < EE
  int r = row_t[e];
  float4 wv = *(const float4*)(w + (size_t)e * 4);
  float wa[4] = {wv.x, wv.y, wv.z, wv.w};
#pragma unroll
  for (int ci = 0; ci < 4; ++ci)
#pragma unroll
    for (int a = 0; a < 3; ++a)
      atomicAdd(&sumv[r * 12 + ci * 3 + a], cd_t[(size_t)e * 12 + ci * 3 + a] * wa[ci]);
  atomicAdd(&cnt[r], 1.f);
}

__global__ __launch_bounds__(256)
void xnew_k(const float* __restrict__ coord, const float* __restrict__ sumv,
            const float* __restrict__ cnt, float* __restrict__ xout)
{
  int id = blockIdx.x * 256 + threadIdx.x;         // < NN*12
  int n = id / 12;
  xout[id] = coord[id] + sumv[id] / fmaxf(cnt[n], 1.f);
}

// ------ m[e] = e1[e,:] . eW2[0,:] + eb2 (one wave per edge) ------
__global__ __launch_bounds__(256)
void mo_k(const float* __restrict__ e1, const float* __restrict__ eW2,
          const float* __restrict__ eb2, float* __restrict__ mout)
{
  int gid = blockIdx.x * 256 + threadIdx.x;
  int wv = gid >> 6;                               // edge id < EE
  int lane = threadIdx.x & 63;
  const float4* hv = (const float4*)(e1 + ((size_t)wv << 9));
  const float4* wp = (const float4*)eW2;
  float4 h0 = hv[lane * 2], h1 = hv[lane * 2 + 1];
  float4 w0 = wp[lane * 2], w1 = wp[lane * 2 + 1];
  float p = h0.x*w0.x + h0.y*w0.y + h0.z*w0.z + h0.w*w0.w
          + h1.x*w1.x + h1.y*w1.y + h1.z*w1.z + h1.w*w1.w;
  p = wave_sum(p);
  if (lane == 0) mout[wv] = p + eb2[0];
}

// ---------------- launch ----------------
extern "C" void kernel_launch(void* const* d_in, const int* in_sizes, int n_in,
                              void* d_out, int out_size, void* d_ws, size_t ws_size,
                              hipStream_t stream)
{
  const float* h     = (const float*)d_in[0];
  const float* coord = (const float*)d_in[1];
  const float* ea    = (const float*)d_in[2];
  const int*   eidx  = (const int*)  d_in[3];
  const float* mW1   = (const float*)d_in[4];
  const float* mb1   = (const float*)d_in[5];
  const float* mW2   = (const float*)d_in[6];
  const float* mb2   = (const float*)d_in[7];
  const float* nW1   = (const float*)d_in[8];
  const float* nb1   = (const float*)d_in[9];
  const float* nW2   = (const float*)d_in[10];
  const float* nb2   = (const float*)d_in[11];
  const float* eW1   = (const float*)d_in[12];
  const float* eb1   = (const float*)d_in[13];
  const float* eW2   = (const float*)d_in[14];
  const float* eb2   = (const float*)d_in[15];
  const float* relW  = (const float*)d_in[16];
  const float* cW1   = (const float*)d_in[17];
  const float* cb1   = (const float*)d_in[18];
  const float* cW2   = (const float*)d_in[19];

  float* out   = (float*)d_out;
  float* out_h = out;                                   // N*D
  float* out_x = out + (size_t)NN * DD;                 // N*C*3
  float* out_m = out_x + (size_t)NN * CC * 3;           // T*E

  // workspace plan (~190 MB total; chunked per relation t)
  char* ws = (char*)d_ws;
  size_t off = 0;
  auto alloc = [&](size_t bytes) -> void* {
    void* p = ws + off; off += (bytes + 255) & ~(size_t)255; return p;
  };
  float* bufA   = (float*)alloc((size_t)EE * 512 * 4);  // 64 MB: msg1 / hid / n1 / e1
  float* bufB   = (float*)alloc((size_t)EE * 512 * 4);  // 64 MB: msg
  float* cd     = (float*)alloc((size_t)TE * 12 * 4);   // 12 MB
  float* radial = (float*)alloc((size_t)TE * 16 * 4);   // 16 MB
  float* segt   = (float*)alloc((size_t)NN * 512 * 4);  // 16 MB
  float* agg    = (float*)alloc((size_t)NN * 512 * 4);  // 16 MB
  float* wbuf   = (float*)alloc((size_t)EE * 4 * 4);    // 0.5 MB
  float* sumv   = (float*)alloc((size_t)NN * 12 * 4);
  float* cnt    = (float*)alloc((size_t)NN * 4);
  float* nrm    = (float*)alloc((size_t)TT * 16 * 4);

  hipMemsetAsync(nrm,  0, (size_t)TT * 16 * 4, stream);
  hipMemsetAsync(agg,  0, (size_t)NN * 512 * 4, stream);
  hipMemsetAsync(sumv, 0, (size_t)NN * 12 * 4, stream);
  hipMemsetAsync(cnt,  0, (size_t)NN * 4, stream);

  // cd, radial (global over all edges)
  cdrad_k<<<TE / 256, 256, 0, stream>>>(coord, eidx, cd, radial, nrm);
  rnorm_k<<<(TE * 16) / 256, 256, 0, stream>>>(radial, nrm);

  const dim3 gE(EE / 128, 4), gN(NN / 128, 4);

  // -------- pass 1: per relation t — msg MLP, seg->agg, coordinate path --------
  for (int t = 0; t < TT; ++t) {
    const int*   row_t = eidx + (size_t)t * 2 * EE;
    const int*   col_t = row_t + EE;
    const float* ea_t  = ea + (size_t)t * EE;
    const float* rad_t = radial + (size_t)t * EE * 16;
    const float* cd_t  = cd + (size_t)t * EE * 12;

    gemm_k<<<gE, 256, 0, stream>>>(AgFeat{h, rad_t, ea_t, row_t, col_t},
        mW1, mb1, nullptr, bufA, 1041, FLAG_SILU);
    gemm_k<<<gE, 256, 0, stream>>>(AgDirect{bufA, 512},
        mW2, mb2, nullptr, bufB, 512, FLAG_SILU);

    hipMemsetAsync(segt, 0, (size_t)NN * 512 * 4, stream);
    segsc_k<<<(EE * 128) / 256, 256, 0, stream>>>(bufB, row_t, segt);
    // agg += segt @ relW[t]^T
    gemm_k<<<gN, 256, 0, stream>>>(AgDirect{segt, 512},
        relW + (size_t)t * 512 * 512, nullptr, agg, agg, 512, FLAG_RES);

    // hid = silu(msg @ cW1[t]^T + cb1[t])
    gemm_k<<<gE, 256, 0, stream>>>(AgDirect{bufB, 512},
        cW1 + (size_t)t * 512 * 512, cb1 + (size_t)t * 512, nullptr, bufA, 512, FLAG_SILU);
    wv_k<<<(EE * 64) / 256, 256, 0, stream>>>(bufA, cW2 + (size_t)t * 4 * 512, wbuf);
    trsc_k<<<EE / 256, 256, 0, stream>>>(cd_t, wbuf, row_t, sumv, cnt);
  }

  // -------- node MLP + residual -> h_new --------
  gemm_k<<<gN, 256, 0, stream>>>(AgHcat{h, agg}, nW1, nb1, nullptr, bufA, 1024, FLAG_SILU);
  gemm_k<<<gN, 256, 0, stream>>>(AgDirect{bufA, 512}, nW2, nb2, h, out_h, 512, FLAG_RES);
  xnew_k<<<(NN * 12) / 256, 256, 0, stream>>>(coord, sumv, cnt, out_x);

  // -------- pass 2: per relation t — edge output MLP --------
  for (int t = 0; t < TT; ++t) {
    const int*   row_t = eidx + (size_t)t * 2 * EE;
    const int*   col_t = row_t + EE;
    const float* ea_t  = ea + (size_t)t * EE;

    gemm_k<<<gE, 256, 0, stream>>>(AgEf{out_h, ea_t, row_t, col_t},
        eW1, eb1, nullptr, bufA, 1025, FLAG_SILU);
    mo_k<<<(EE * 64) / 256, 256, 0, stream>>>(bufA, eW2, eb2, out_m + (size_t)t * EE);
  }

  (void)in_sizes; (void)n_in; (void)out_size; (void)ws_size;
}

// Round 3
// 5507.573 us; speedup vs baseline: 6.0311x; 6.0311x over previous
//
#include <hip/hip_runtime.h>
#include <cstdint>

#define NN 8192
#define DD 512
#define CC 4
#define TT 8
#define EE 32768
#define TE (TT*EE)

typedef __attribute__((ext_vector_type(8))) short short8v;
typedef __attribute__((ext_vector_type(4))) float f32x4;

constexpr int FLAG_SILU = 1, FLAG_RES = 2;

__device__ __forceinline__ float silu_f(float x) { return x / (1.f + __expf(-x)); }

__device__ __forceinline__ unsigned short f2bf(float f) {
  unsigned int u = __builtin_bit_cast(unsigned int, f);
  u += 0x7fffu + ((u >> 16) & 1u);
  return (unsigned short)(u >> 16);
}
__device__ __forceinline__ float bf2f(unsigned short b) {
  unsigned int u = ((unsigned int)b) << 16;
  return __builtin_bit_cast(float, u);
}

__device__ __forceinline__ float wave_sum(float v) {
#pragma unroll
  for (int off = 32; off; off >>= 1) v += __shfl_xor(v, off);
  return v;
}

__device__ __forceinline__ void gload16(const void* g, void* l) {
  __builtin_amdgcn_global_load_lds(
      (const __attribute__((address_space(1))) void*)g,
      (__attribute__((address_space(3))) void*)l, 16, 0, 0);
}

// ---------------- A-side gather functors: return 16B-aligned source ptr for (row m, k..k+7) ----------------
struct AgDirect { const unsigned short* p; int K;
  __device__ const void* ptr(int m, int k) const { return p + (size_t)m * K + k; } };

struct AgFeat { const unsigned short* h; const unsigned short* tail; const unsigned short* zp;
                const int* row; const int* col;
  __device__ const void* ptr(int m, int k) const {
    if (k < 512)  return h + ((size_t)row[m] << 9) + k;
    if (k < 1024) return h + ((size_t)col[m] << 9) + (k - 512);
    int kk = k - 1024;                 // 0..56, step 8; tail row = rad16|ea|0x7 (24 elems)
    return (kk < 24) ? (const void*)(tail + (size_t)m * 24 + kk) : (const void*)zp; } };

struct AgEf { const unsigned short* hn; const unsigned short* tail; const unsigned short* zp;
              const int* row; const int* col;
  __device__ const void* ptr(int m, int k) const {
    if (k < 512)  return hn + ((size_t)row[m] << 9) + k;
    if (k < 1024) return hn + ((size_t)col[m] << 9) + (k - 512);
    int kk = k - 1024;                 // tail row = ea|0x7 (8 elems)
    return (kk < 8) ? (const void*)(tail + (size_t)m * 8 + kk) : (const void*)zp; } };

struct AgHcat { const unsigned short* hb; const unsigned short* ab;
  __device__ const void* ptr(int m, int k) const {
    return (k < 512) ? (const void*)(hb + ((size_t)m << 9) + k)
                     : (const void*)(ab + ((size_t)m << 9) + (k - 512)); } };

// ---------------- bf16 MFMA GEMM: out[m][o] = act(A[m,:] . W[o,:] + b[o]) (+res). O always 512 wide ----------------
template<class AG>
__global__ __launch_bounds__(256)
void mgemm_k(AG ag, const unsigned short* __restrict__ wgt, int K,
             const float* __restrict__ bias, const float* __restrict__ res,
             float* __restrict__ outF, unsigned short* __restrict__ outB, int flags)
{
  __shared__ __align__(16) unsigned short As[128 * 64];
  __shared__ __align__(16) unsigned short Bs[128 * 64];
  const int m0 = blockIdx.x * 128, o0 = blockIdx.y * 128;
  const int tid = threadIdx.x, wave = tid >> 6, lane = tid & 63;
  const int wr = (wave >> 1) * 64, wc = (wave & 1) * 64;
  const int rs = lane >> 3, sl = lane & 7;

  f32x4 acc[4][4];
#pragma unroll
  for (int i = 0; i < 4; ++i)
#pragma unroll
    for (int j = 0; j < 4; ++j) acc[i][j] = (f32x4)0.f;

  for (int k0 = 0; k0 < K; k0 += 64) {
#pragma unroll
    for (int i = 0; i < 4; ++i) {
      int r = i * 32 + wave * 8 + rs;
      int slot = sl ^ (r & 7);                       // pre-swizzled global source
      gload16(ag.ptr(m0 + r, k0 + slot * 8), &As[(i * 32 + wave * 8) * 64]);
    }
#pragma unroll
    for (int i = 0; i < 4; ++i) {
      int r = i * 32 + wave * 8 + rs;
      int slot = sl ^ (r & 7);
      gload16(wgt + (size_t)(o0 + r) * K + k0 + slot * 8, &Bs[(i * 32 + wave * 8) * 64]);
    }
    __syncthreads();

    short8v a[4][2], b[4][2];
#pragma unroll
    for (int mi = 0; mi < 4; ++mi)
#pragma unroll
      for (int s = 0; s < 2; ++s) {
        int row = wr + mi * 16 + (lane & 15);
        int slot = (s * 4 + (lane >> 4)) ^ (row & 7);
        a[mi][s] = *(const short8v*)&As[row * 64 + slot * 8];
      }
#pragma unroll
    for (int ni = 0; ni < 4; ++ni)
#pragma unroll
      for (int s = 0; s < 2; ++s) {
        int row = wc + ni * 16 + (lane & 15);
        int slot = (s * 4 + (lane >> 4)) ^ (row & 7);
        b[ni][s] = *(const short8v*)&Bs[row * 64 + slot * 8];
      }
#pragma unroll
    for (int s = 0; s < 2; ++s)
#pragma unroll
      for (int mi = 0; mi < 4; ++mi)
#pragma unroll
        for (int ni = 0; ni < 4; ++ni)
          acc[mi][ni] = __builtin_amdgcn_mfma_f32_16x16x32_bf16(a[mi][s], b[ni][s], acc[mi][ni], 0, 0, 0);
    __syncthreads();
  }

  const int r4 = (lane >> 4) * 4, cl = lane & 15;
#pragma unroll
  for (int mi = 0; mi < 4; ++mi)
#pragma unroll
    for (int ni = 0; ni < 4; ++ni)
#pragma unroll
      for (int rg = 0; rg < 4; ++rg) {
        int row = m0 + wr + mi * 16 + r4 + rg;
        int col = o0 + wc + ni * 16 + cl;
        float v = acc[mi][ni][rg];
        if (bias) v += bias[col];
        if (flags & FLAG_SILU) v = silu_f(v);
        if (flags & FLAG_RES) v += res[(size_t)row * 512 + col];
        if (outF) outF[(size_t)row * 512 + col] = v;
        if (outB) outB[(size_t)row * 512 + col] = f2bf(v);
      }
}

// ---------------- prep kernels ----------------
__global__ __launch_bounds__(256)
void cvt_k(const float* __restrict__ in, unsigned short* __restrict__ out, int n) {
  int i = blockIdx.x * 256 + threadIdx.x;
  if (i < n) out[i] = f2bf(in[i]);
}

__global__ __launch_bounds__(256)
void padw_k(const float* __restrict__ w, unsigned short* __restrict__ o, int Kin, int Kout, int n) {
  int i = blockIdx.x * 256 + threadIdx.x;
  if (i >= n) return;
  int r = i / Kout, k = i - r * Kout;
  o[i] = (k < Kin) ? f2bf(w[(size_t)r * Kin + k]) : 0;
}

// eW1 (512 x 1025, order hn_row|ea|hn_col) -> (512 x 1088, order hn_row|hn_col|ea|0)
__global__ __launch_bounds__(256)
void permw_k(const float* __restrict__ w, unsigned short* __restrict__ o, int n) {
  int i = blockIdx.x * 256 + threadIdx.x;
  if (i >= n) return;
  int r = i / 1088, k = i - r * 1088;
  float v = 0.f;
  if (k < 512)       v = w[(size_t)r * 1025 + k];
  else if (k < 1024) v = w[(size_t)r * 1025 + k + 1];
  else if (k == 1024) v = w[(size_t)r * 1025 + 512];
  o[i] = f2bf(v);
}

// ---------------- cd / radial / per-(t,c,d) sq-sum partials ----------------
__global__ __launch_bounds__(256)
void cdrad_k(const float* __restrict__ coord, const int* __restrict__ eidx,
             float* __restrict__ cd, float* __restrict__ radial, float* __restrict__ nrm)
{
  int m = blockIdx.x * 256 + threadIdx.x;          // < TE
  int t = m >> 15, e = m & (EE - 1);
  int r = eidx[(t << 16) + e], c = eidx[(t << 16) + EE + e];
  float d[12];
#pragma unroll
  for (int i = 0; i < 12; ++i) d[i] = coord[r * 12 + i] - coord[c * 12 + i];
#pragma unroll
  for (int i = 0; i < 12; ++i) cd[(size_t)m * 12 + i] = d[i];
  float sq[16];
#pragma unroll
  for (int ci = 0; ci < 4; ++ci)
#pragma unroll
    for (int di = 0; di < 4; ++di) {
      float v = d[ci*3]*d[di*3] + d[ci*3+1]*d[di*3+1] + d[ci*3+2]*d[di*3+2];
      radial[(size_t)m * 16 + ci * 4 + di] = v;
      sq[ci * 4 + di] = v * v;
    }
#pragma unroll
  for (int i = 0; i < 16; ++i) sq[i] = wave_sum(sq[i]);
  if ((threadIdx.x & 63) == 0) {
#pragma unroll
    for (int i = 0; i < 16; ++i) atomicAdd(&nrm[t * 16 + i], sq[i]);
  }
}

// tail_m row (24): rad_norm(16)|ea|0*7 ; tail_e row (8): ea|0*7
__global__ __launch_bounds__(256)
void tails_k(const float* __restrict__ radial, const float* __restrict__ nrm,
             const float* __restrict__ ea,
             unsigned short* __restrict__ tailm, unsigned short* __restrict__ taile)
{
  int m = blockIdx.x * 256 + threadIdx.x;          // < TE
  int t = m >> 15;
#pragma unroll
  for (int j = 0; j < 16; ++j) {
    float r = radial[(size_t)m * 16 + j] / fmaxf(sqrtf(nrm[t * 16 + j]), 1e-12f);
    tailm[(size_t)m * 24 + j] = f2bf(r);
  }
  float e = ea[m];
  tailm[(size_t)m * 24 + 16] = f2bf(e);
#pragma unroll
  for (int j = 17; j < 24; ++j) tailm[(size_t)m * 24 + j] = 0;
  taile[(size_t)m * 8 + 0] = f2bf(e);
#pragma unroll
  for (int j = 1; j < 8; ++j) taile[(size_t)m * 8 + j] = 0;
}

// ---------------- segment sum of msg (bf16) into segt (N, 512) f32 ----------------
__global__ __launch_bounds__(256)
void segsc_k(const unsigned short* __restrict__ msg, const int* __restrict__ row_t,
             float* __restrict__ segt)
{
  int id = blockIdx.x * 256 + threadIdx.x;         // < EE*128
  int e = id >> 7, part = (id & 127) << 2;
  int r = row_t[e];
  const unsigned short* mp = msg + ((size_t)e << 9) + part;
  float* s = segt + ((size_t)r << 9) + part;
  atomicAdd(s + 0, bf2f(mp[0])); atomicAdd(s + 1, bf2f(mp[1]));
  atomicAdd(s + 2, bf2f(mp[2])); atomicAdd(s + 3, bf2f(mp[3]));
}

// ------ w[e,c] = hid[e,:] . cW2t[c,:] (one wave per edge; hid bf16) ------
__global__ __launch_bounds__(256)
void wv_k(const unsigned short* __restrict__ hid, const float* __restrict__ cW2t,
          float* __restrict__ w)
{
  int gid = blockIdx.x * 256 + threadIdx.x;
  int wv = gid >> 6;                               // edge id < EE
  int lane = threadIdx.x & 63;
  short8v hv = *(const short8v*)(hid + ((size_t)wv << 9) + lane * 8);
  float hf[8];
#pragma unroll
  for (int j = 0; j < 8; ++j) hf[j] = bf2f((unsigned short)hv[j]);
  float p[4];
#pragma unroll
  for (int c = 0; c < 4; ++c) {
    const float4* wp = (const float4*)(cW2t + ((size_t)c << 9) + lane * 8);
    float4 w0 = wp[0], w1 = wp[1];
    p[c] = hf[0]*w0.x + hf[1]*w0.y + hf[2]*w0.z + hf[3]*w0.w
         + hf[4]*w1.x + hf[5]*w1.y + hf[6]*w1.z + hf[7]*w1.w;
  }
#pragma unroll
  for (int c = 0; c < 4; ++c) p[c] = wave_sum(p[c]);
  if (lane == 0) {
    float4 o; o.x = p[0]; o.y = p[1]; o.z = p[2]; o.w = p[3];
    *(float4*)(w + (size_t)wv * 4) = o;
  }
}

// ---------------- trans scatter: sumv += cd*w, cnt += 1 ----------------
__global__ __launch_bounds__(256)
void trsc_k(const float* __restrict__ cd_t, const float* __restrict__ w,
            const int* __restrict__ row_t, float* __restrict__ sumv, float* __restrict__ cnt)
{
  int e = blockIdx.x * 256 + threadIdx.x;          // < EE
  int r = row_t[e];
  float4 wvv = *(const float4*)(w + (size_t)e * 4);
  float wa[4] = {wvv.x, wvv.y, wvv.z, wvv.w};
#pragma unroll
  for (int ci = 0; ci < 4; ++ci)
#pragma unroll
    for (int a = 0; a < 3; ++a)
      atomicAdd(&sumv[r * 12 + ci * 3 + a], cd_t[(size_t)e * 12 + ci * 3 + a] * wa[ci]);
  atomicAdd(&cnt[r], 1.f);
}

__global__ __launch_bounds__(256)
void xnew_k(const float* __restrict__ coord, const float* __restrict__ sumv,
            const float* __restrict__ cnt, float* __restrict__ xout)
{
  int id = blockIdx.x * 256 + threadIdx.x;         // < NN*12
  int n = id / 12;
  xout[id] = coord[id] + sumv[id] / fmaxf(cnt[n], 1.f);
}

// ------ m[e] = e1[e,:] . eW2[0,:] + eb2 (one wave per edge; e1 bf16) ------
__global__ __launch_bounds__(256)
void mo_k(const unsigned short* __restrict__ e1, const float* __restrict__ eW2,
          const float* __restrict__ eb2, float* __restrict__ mout)
{
  int gid = blockIdx.x * 256 + threadIdx.x;
  int wv = gid >> 6;                               // edge id < EE
  int lane = threadIdx.x & 63;
  short8v hv = *(const short8v*)(e1 + ((size_t)wv << 9) + lane * 8);
  const float4* wp = (const float4*)(eW2 + lane * 8);
  float4 w0 = wp[0], w1 = wp[1];
  float p = bf2f((unsigned short)hv[0])*w0.x + bf2f((unsigned short)hv[1])*w0.y
          + bf2f((unsigned short)hv[2])*w0.z + bf2f((unsigned short)hv[3])*w0.w
          + bf2f((unsigned short)hv[4])*w1.x + bf2f((unsigned short)hv[5])*w1.y
          + bf2f((unsigned short)hv[6])*w1.z + bf2f((unsigned short)hv[7])*w1.w;
  p = wave_sum(p);
  if (lane == 0) mout[wv] = p + eb2[0];
}

// ---------------- launch ----------------
extern "C" void kernel_launch(void* const* d_in, const int* in_sizes, int n_in,
                              void* d_out, int out_size, void* d_ws, size_t ws_size,
                              hipStream_t stream)
{
  const float* h     = (const float*)d_in[0];
  const float* coord = (const float*)d_in[1];
  const float* ea    = (const float*)d_in[2];
  const int*   eidx  = (const int*)  d_in[3];
  const float* mW1   = (const float*)d_in[4];
  const float* mb1   = (const float*)d_in[5];
  const float* mW2   = (const float*)d_in[6];
  const float* mb2   = (const float*)d_in[7];
  const float* nW1   = (const float*)d_in[8];
  const float* nb1   = (const float*)d_in[9];
  const float* nW2   = (const float*)d_in[10];
  const float* nb2   = (const float*)d_in[11];
  const float* eW1   = (const float*)d_in[12];
  const float* eb1   = (const float*)d_in[13];
  const float* eW2   = (const float*)d_in[14];
  const float* eb2   = (const float*)d_in[15];
  const float* relW  = (const float*)d_in[16];
  const float* cW1   = (const float*)d_in[17];
  const float* cb1   = (const float*)d_in[18];
  const float* cW2   = (const float*)d_in[19];

  float* out   = (float*)d_out;
  float* out_h = out;                                   // N*D
  float* out_x = out + (size_t)NN * DD;                 // N*C*3
  float* out_m = out_x + (size_t)NN * CC * 3;           // T*E

  char* ws = (char*)d_ws;
  size_t off = 0;
  auto alloc = [&](size_t bytes) -> void* {
    void* p = ws + off; off += (bytes + 255) & ~(size_t)255; return p;
  };
  unsigned short* bufA  = (unsigned short*)alloc((size_t)EE * 512 * 2);   // 32 MB (aliases radial early)
  unsigned short* bufB  = (unsigned short*)alloc((size_t)EE * 512 * 2);   // 32 MB
  float* cd     = (float*)alloc((size_t)TE * 12 * 4);                     // 12.6 MB
  unsigned short* tailm = (unsigned short*)alloc((size_t)TE * 24 * 2);    // 12.6 MB
  unsigned short* taile = (unsigned short*)alloc((size_t)TE * 8 * 2);     // 4.2 MB
  float* segt   = (float*)alloc((size_t)NN * 512 * 4);                    // 16.8 MB
  unsigned short* segtb = (unsigned short*)alloc((size_t)NN * 512 * 2);   // 8.4 MB
  float* agg    = (float*)alloc((size_t)NN * 512 * 4);                    // 16.8 MB
  unsigned short* aggb  = (unsigned short*)alloc((size_t)NN * 512 * 2);   // 8.4 MB
  unsigned short* h_bf  = (unsigned short*)alloc((size_t)NN * 512 * 2);   // 8.4 MB
  unsigned short* hn_bf = (unsigned short*)alloc((size_t)NN * 512 * 2);   // 8.4 MB
  unsigned short* mW1b  = (unsigned short*)alloc((size_t)512 * 1088 * 2);
  unsigned short* mW2b  = (unsigned short*)alloc((size_t)512 * 512 * 2);
  unsigned short* nW1b  = (unsigned short*)alloc((size_t)512 * 1024 * 2);
  unsigned short* nW2b  = (unsigned short*)alloc((size_t)512 * 512 * 2);
  unsigned short* eW1b  = (unsigned short*)alloc((size_t)512 * 1088 * 2);
  unsigned short* relWb = (unsigned short*)alloc((size_t)TT * 512 * 512 * 2);
  unsigned short* cW1b  = (unsigned short*)alloc((size_t)TT * 512 * 512 * 2);
  float* wbuf   = (float*)alloc((size_t)EE * 4 * 4);
  float* sumv   = (float*)alloc((size_t)NN * 12 * 4);
  float* cnt    = (float*)alloc((size_t)NN * 4);
  float* nrm    = (float*)alloc((size_t)TT * 16 * 4);
  unsigned short* zp = (unsigned short*)alloc(256);
  float* radial = (float*)bufA;   // alias: radial (TE*16 f32 = 16.8 MB) lives in bufA until tails_k done

  hipMemsetAsync(nrm,  0, (size_t)TT * 16 * 4, stream);
  hipMemsetAsync(agg,  0, (size_t)NN * 512 * 4, stream);
  hipMemsetAsync(sumv, 0, (size_t)NN * 12 * 4, stream);
  hipMemsetAsync(cnt,  0, (size_t)NN * 4, stream);
  hipMemsetAsync(zp,   0, 256, stream);

  // ---- prep: bf16 conversions ----
  auto cvt = [&](const float* in, unsigned short* o, int n) {
    cvt_k<<<(n + 255) / 256, 256, 0, stream>>>(in, o, n);
  };
  cvt(h,    h_bf,  NN * 512);
  cvt(mW2,  mW2b,  512 * 512);
  cvt(nW1,  nW1b,  512 * 1024);
  cvt(nW2,  nW2b,  512 * 512);
  cvt(relW, relWb, TT * 512 * 512);
  cvt(cW1,  cW1b,  TT * 512 * 512);
  padw_k<<<(512 * 1088 + 255) / 256, 256, 0, stream>>>(mW1, mW1b, 1041, 1088, 512 * 1088);
  permw_k<<<(512 * 1088 + 255) / 256, 256, 0, stream>>>(eW1, eW1b, 512 * 1088);

  // ---- geometry ----
  cdrad_k<<<TE / 256, 256, 0, stream>>>(coord, eidx, cd, radial, nrm);
  tails_k<<<TE / 256, 256, 0, stream>>>(radial, nrm, ea, tailm, taile);

  const dim3 gE(EE / 128, 4), gN(NN / 128, 4);

  // -------- pass 1: per relation t --------
  for (int t = 0; t < TT; ++t) {
    const int* row_t = eidx + (size_t)t * 2 * EE;
    const int* col_t = row_t + EE;
    const unsigned short* tailm_t = tailm + (size_t)t * EE * 24;
    const float* cd_t = cd + (size_t)t * EE * 12;

    mgemm_k<<<gE, 256, 0, stream>>>(AgFeat{h_bf, tailm_t, zp, row_t, col_t},
        mW1b, 1088, mb1, nullptr, nullptr, bufA, FLAG_SILU);
    mgemm_k<<<gE, 256, 0, stream>>>(AgDirect{bufA, 512},
        mW2b, 512, mb2, nullptr, nullptr, bufB, FLAG_SILU);

    hipMemsetAsync(segt, 0, (size_t)NN * 512 * 4, stream);
    segsc_k<<<(EE * 128) / 256, 256, 0, stream>>>(bufB, row_t, segt);
    cvt(segt, segtb, NN * 512);
    mgemm_k<<<gN, 256, 0, stream>>>(AgDirect{segtb, 512},
        relWb + (size_t)t * 512 * 512, 512, nullptr, agg, agg, nullptr, FLAG_RES);

    mgemm_k<<<gE, 256, 0, stream>>>(AgDirect{bufB, 512},
        cW1b + (size_t)t * 512 * 512, 512, cb1 + (size_t)t * 512, nullptr, nullptr, bufA, FLAG_SILU);
    wv_k<<<(EE * 64) / 256, 256, 0, stream>>>(bufA, cW2 + (size_t)t * 4 * 512, wbuf);
    trsc_k<<<EE / 256, 256, 0, stream>>>(cd_t, wbuf, row_t, sumv, cnt);
  }

  // -------- node MLP + residual -> h_new (f32 out + bf16 copy) --------
  cvt(agg, aggb, NN * 512);
  mgemm_k<<<gN, 256, 0, stream>>>(AgHcat{h_bf, aggb},
      nW1b, 1024, nb1, nullptr, nullptr, bufA, FLAG_SILU);
  mgemm_k<<<gN, 256, 0, stream>>>(AgDirect{bufA, 512},
      nW2b, 512, nb2, h, out_h, hn_bf, FLAG_RES);
  xnew_k<<<(NN * 12) / 256, 256, 0, stream>>>(coord, sumv, cnt, out_x);

  // -------- pass 2: per relation t — edge output MLP --------
  for (int t = 0; t < TT; ++t) {
    const int* row_t = eidx + (size_t)t * 2 * EE;
    const int* col_t = row_t + EE;
    const unsigned short* taile_t = taile + (size_t)t * EE * 8;

    mgemm_k<<<gE, 256, 0, stream>>>(AgEf{hn_bf, taile_t, zp, row_t, col_t},
        eW1b, 1088, eb1, nullptr, nullptr, bufA, FLAG_SILU);
    mo_k<<<(EE * 64) / 256, 256, 0, stream>>>(bufA, eW2, eb2, out_m + (size_t)t * EE);
  }

  (void)in_sizes; (void)n_in; (void)out_size; (void)ws_size;
}

// Round 4
// 2231.580 us; speedup vs baseline: 14.8849x; 2.4680x over previous
//
#include <hip/hip_runtime.h>
#include <cstdint>

#define NN 8192
#define DD 512
#define CC 4
#define TT 8
#define EE 32768
#define TE (TT*EE)

typedef __attribute__((ext_vector_type(8))) short short8v;
typedef __attribute__((ext_vector_type(4))) float f32x4;
typedef unsigned int uint;

constexpr int FLAG_SILU = 1, FLAG_RES = 2;

__device__ __forceinline__ float silu_f(float x) { return x / (1.f + __expf(-x)); }

__device__ __forceinline__ unsigned short f2bf(float f) {
  uint u = __builtin_bit_cast(uint, f);
  u += 0x7fffu + ((u >> 16) & 1u);
  return (unsigned short)(u >> 16);
}
__device__ __forceinline__ float bf2f(unsigned short b) {
  uint u = ((uint)b) << 16;
  return __builtin_bit_cast(float, u);
}
__device__ __forceinline__ float bflo(uint u) { return __builtin_bit_cast(float, u << 16); }
__device__ __forceinline__ float bfhi(uint u) { return __builtin_bit_cast(float, u & 0xffff0000u); }
__device__ __forceinline__ uint packbf(float a, float b) {
  return (uint)f2bf(a) | ((uint)f2bf(b) << 16);
}

__device__ __forceinline__ float wave_sum(float v) {
#pragma unroll
  for (int off = 32; off; off >>= 1) v += __shfl_xor(v, off);
  return v;
}

__device__ __forceinline__ void gload16(const void* g, void* l) {
  __builtin_amdgcn_global_load_lds(
      (const __attribute__((address_space(1))) void*)g,
      (__attribute__((address_space(3))) void*)l, 16, 0, 0);
}

// ---------------- A-side gather functors ----------------
struct AgDirect { const unsigned short* p; int K;
  __device__ const void* ptr(int m, int k) const { return p + (size_t)m * K + k; } };

struct AgHcat { const unsigned short* hb; const unsigned short* ab;
  __device__ const void* ptr(int m, int k) const {
    return (k < 512) ? (const void*)(hb + ((size_t)m << 9) + k)
                     : (const void*)(ab + ((size_t)m << 9) + (k - 512)); } };

// ------- bf16 MFMA GEMM: out[m][o] = act(A[m,:] . W[o,:] + b[o]) (+res). O = 512 -------
template<class AG>
__global__ __launch_bounds__(256)
void mgemm_k(AG ag, const unsigned short* __restrict__ wgt, int K,
             const float* __restrict__ bias, const float* __restrict__ res,
             float* __restrict__ outF, unsigned short* __restrict__ outB, int flags)
{
  __shared__ __align__(16) unsigned short As[128 * 64];
  __shared__ __align__(16) unsigned short Bs[128 * 64];
  const int m0 = blockIdx.x * 128, o0 = blockIdx.y * 128;
  const int tid = threadIdx.x, wave = tid >> 6, lane = tid & 63;
  const int wr = (wave >> 1) * 64, wc = (wave & 1) * 64;
  const int rs = lane >> 3, sl = lane & 7;

  f32x4 acc[4][4];
#pragma unroll
  for (int i = 0; i < 4; ++i)
#pragma unroll
    for (int j = 0; j < 4; ++j) acc[i][j] = (f32x4)0.f;

  for (int k0 = 0; k0 < K; k0 += 64) {
#pragma unroll
    for (int i = 0; i < 4; ++i) {
      int r = i * 32 + wave * 8 + rs;
      int slot = sl ^ (r & 7);
      gload16(ag.ptr(m0 + r, k0 + slot * 8), &As[(i * 32 + wave * 8) * 64]);
    }
#pragma unroll
    for (int i = 0; i < 4; ++i) {
      int r = i * 32 + wave * 8 + rs;
      int slot = sl ^ (r & 7);
      gload16(wgt + (size_t)(o0 + r) * K + k0 + slot * 8, &Bs[(i * 32 + wave * 8) * 64]);
    }
    __syncthreads();

    short8v a[4][2], b[4][2];
#pragma unroll
    for (int mi = 0; mi < 4; ++mi)
#pragma unroll
      for (int s = 0; s < 2; ++s) {
        int row = wr + mi * 16 + (lane & 15);
        int slot = (s * 4 + (lane >> 4)) ^ (row & 7);
        a[mi][s] = *(const short8v*)&As[row * 64 + slot * 8];
      }
#pragma unroll
    for (int ni = 0; ni < 4; ++ni)
#pragma unroll
      for (int s = 0; s < 2; ++s) {
        int row = wc + ni * 16 + (lane & 15);
        int slot = (s * 4 + (lane >> 4)) ^ (row & 7);
        b[ni][s] = *(const short8v*)&Bs[row * 64 + slot * 8];
      }
#pragma unroll
    for (int s = 0; s < 2; ++s)
#pragma unroll
      for (int mi = 0; mi < 4; ++mi)
#pragma unroll
        for (int ni = 0; ni < 4; ++ni)
          acc[mi][ni] = __builtin_amdgcn_mfma_f32_16x16x32_bf16(a[mi][s], b[ni][s], acc[mi][ni], 0, 0, 0);
    __syncthreads();
  }

  const int r4 = (lane >> 4) * 4, cl = lane & 15;
#pragma unroll
  for (int mi = 0; mi < 4; ++mi)
#pragma unroll
    for (int ni = 0; ni < 4; ++ni)
#pragma unroll
      for (int rg = 0; rg < 4; ++rg) {
        int row = m0 + wr + mi * 16 + r4 + rg;
        int col = o0 + wc + ni * 16 + cl;
        float v = acc[mi][ni][rg];
        if (bias) v += bias[col];
        if (flags & FLAG_SILU) v = silu_f(v);
        if (flags & FLAG_RES) v += res[(size_t)row * 512 + col];
        if (outF) outF[(size_t)row * 512 + col] = v;
        if (outB) outB[(size_t)row * 512 + col] = f2bf(v);
      }
}

// ---------------- prep kernels ----------------
__global__ __launch_bounds__(256)
void cvt_k(const float* __restrict__ in, unsigned short* __restrict__ out, int n) {
  int i = blockIdx.x * 256 + threadIdx.x;
  if (i < n) out[i] = f2bf(in[i]);
}

// dst[r][k] = src[r*Kin + col0 + k], dst 512x512 bf16
__global__ __launch_bounds__(256)
void slicew_k(const float* __restrict__ w, unsigned short* __restrict__ o, int Kin, int col0) {
  int i = blockIdx.x * 256 + threadIdx.x;   // < 512*512
  int r = i >> 9, k = i & 511;
  o[i] = f2bf(w[(size_t)r * Kin + col0 + k]);
}

// Wt[j][o] = mW1[o][1024+j], j<17
__global__ __launch_bounds__(256)
void tailw_k(const float* __restrict__ mW1, unsigned short* __restrict__ o) {
  int i = blockIdx.x * 256 + threadIdx.x;   // < 17*512
  if (i >= 17 * 512) return;
  int j = i >> 9, c = i & 511;
  o[i] = f2bf(mW1[(size_t)c * 1041 + 1024 + j]);
}

__global__ __launch_bounds__(256)
void weaw_k(const float* __restrict__ eW1, float* __restrict__ wea) {
  int i = blockIdx.x * 256 + threadIdx.x;   // < 512
  if (i < 512) wea[i] = eW1[(size_t)i * 1025 + 512];
}

// ---------------- cd / radial / per-block sq-sum partials ----------------
__global__ __launch_bounds__(256)
void cdrad_k(const float* __restrict__ coord, const int* __restrict__ eidx,
             float* __restrict__ cd, float* __restrict__ radial, float* __restrict__ pnrm)
{
  int m = blockIdx.x * 256 + threadIdx.x;          // < TE
  int t = m >> 15, e = m & (EE - 1);
  int r = eidx[(t << 16) + e], c = eidx[(t << 16) + EE + e];
  const float4* cv4 = (const float4*)coord;
  float4 A0 = cv4[r * 3], A1 = cv4[r * 3 + 1], A2 = cv4[r * 3 + 2];
  float4 B0 = cv4[c * 3], B1 = cv4[c * 3 + 1], B2 = cv4[c * 3 + 2];
  float d[12] = {A0.x-B0.x, A0.y-B0.y, A0.z-B0.z, A0.w-B0.w,
                 A1.x-B1.x, A1.y-B1.y, A1.z-B1.z, A1.w-B1.w,
                 A2.x-B2.x, A2.y-B2.y, A2.z-B2.z, A2.w-B2.w};
  float4* cdv = (float4*)cd;
  cdv[m*3+0] = make_float4(d[0],d[1],d[2],d[3]);
  cdv[m*3+1] = make_float4(d[4],d[5],d[6],d[7]);
  cdv[m*3+2] = make_float4(d[8],d[9],d[10],d[11]);
  float rad[16], sq[16];
#pragma unroll
  for (int ci = 0; ci < 4; ++ci)
#pragma unroll
    for (int di = 0; di < 4; ++di) {
      float v = d[ci*3]*d[di*3] + d[ci*3+1]*d[di*3+1] + d[ci*3+2]*d[di*3+2];
      rad[ci*4+di] = v; sq[ci*4+di] = v * v;
    }
  float4* rv = (float4*)radial;
#pragma unroll
  for (int i = 0; i < 4; ++i)
    rv[m*4+i] = make_float4(rad[i*4], rad[i*4+1], rad[i*4+2], rad[i*4+3]);
#pragma unroll
  for (int i = 0; i < 16; ++i) sq[i] = wave_sum(sq[i]);
  __shared__ float red[4][16];
  int wave = threadIdx.x >> 6, lane = threadIdx.x & 63;
  if (lane == 0) {
#pragma unroll
    for (int i = 0; i < 16; ++i) red[wave][i] = sq[i];
  }
  __syncthreads();
  if (threadIdx.x < 16)
    pnrm[blockIdx.x * 16 + threadIdx.x] =
        red[0][threadIdx.x] + red[1][threadIdx.x] + red[2][threadIdx.x] + red[3][threadIdx.x];
}

// reduce pnrm (128 blocks per t) -> nrm[t*16+j]
__global__ __launch_bounds__(128)
void nrmred_k(const float* __restrict__ pnrm, float* __restrict__ nrm) {
  int t = threadIdx.x >> 4, j = threadIdx.x & 15;
  float s = 0.f;
  for (int b = 0; b < 128; ++b) s += pnrm[((t * 128 + b) << 4) + j];
  nrm[(t << 4) + j] = s;
}

// tail row (24): rad_norm(16)|ea|0*7
__global__ __launch_bounds__(256)
void tails_k(const float* __restrict__ radial, const float* __restrict__ nrm,
             const float* __restrict__ ea, unsigned short* __restrict__ tailm)
{
  int m = blockIdx.x * 256 + threadIdx.x;          // < TE
  int t = m >> 15;
  unsigned short tmp[24];
#pragma unroll
  for (int j = 0; j < 16; ++j) {
    float r = radial[(size_t)m * 16 + j] / fmaxf(sqrtf(nrm[(t << 4) + j]), 1e-12f);
    tmp[j] = f2bf(r);
  }
  tmp[16] = f2bf(ea[m]);
#pragma unroll
  for (int j = 17; j < 24; ++j) tmp[j] = 0;
  uint4* dst = (uint4*)(tailm + (size_t)m * 24);
  dst[0] = ((const uint4*)tmp)[0];
  dst[1] = ((const uint4*)tmp)[1];
  dst[2] = ((const uint4*)tmp)[2];
}

// ---------------- counting sort of edges by destination node ----------------
__global__ __launch_bounds__(256)
void hist_k(const int* __restrict__ eidx, int* __restrict__ deg) {
  int id = blockIdx.x * 256 + threadIdx.x;         // < TE
  int t = id >> 15, e = id & (EE - 1);
  int r = eidx[(t << 16) + e];
  atomicAdd(&deg[(t << 13) + r], 1);
}

__global__ __launch_bounds__(256)
void scan_k(const int* __restrict__ deg, int* __restrict__ off, int* __restrict__ cursor) {
  int t = blockIdx.x, tid = threadIdx.x;
  __shared__ int lds[256];
  int base = 0;
  for (int ch = 0; ch < 32; ++ch) {
    int i = ch * 256 + tid;
    int v = deg[(t << 13) + i];
    __syncthreads();
    lds[tid] = v;
    __syncthreads();
    for (int s = 1; s < 256; s <<= 1) {
      int x = (tid >= s) ? lds[tid - s] : 0;
      __syncthreads();
      if (tid >= s) lds[tid] += x;
      __syncthreads();
    }
    int excl = base + lds[tid] - v;
    off[(t << 13) + i] = excl;
    cursor[(t << 13) + i] = excl;
    base += lds[255];
  }
}

__global__ __launch_bounds__(256)
void scat_k(const int* __restrict__ eidx, int* __restrict__ cursor, int* __restrict__ order) {
  int id = blockIdx.x * 256 + threadIdx.x;         // < TE
  int t = id >> 15, e = id & (EE - 1);
  int r = eidx[(t << 16) + e];
  int pos = atomicAdd(&cursor[(t << 13) + r], 1);
  order[(size_t)t * EE + pos] = e;
}

// gather-sum: seg[n] = sum of msg rows of node n's edges (per t)
__global__ __launch_bounds__(256)
void gsum_k(const unsigned short* __restrict__ msg, const int* __restrict__ off_t,
            const int* __restrict__ deg_t, const int* __restrict__ order_t,
            unsigned short* __restrict__ segtb)
{
  int n = blockIdx.x, tid = threadIdx.x;
  int start = off_t[n], d = deg_t[n];
  float s0 = 0.f, s1 = 0.f;
  for (int j = 0; j < d; ++j) {
    int e = order_t[start + j];
    uint v = *(const uint*)(msg + ((size_t)e << 9) + tid * 2);
    s0 += bflo(v); s1 += bfhi(v);
  }
  *(uint*)(segtb + ((size_t)n << 9) + tid * 2) = packbf(s0, s1);
}

// ---------------- fused msg1: silu(P[row]+Q[col]+tail·Wt) ----------------
__global__ __launch_bounds__(256)
void msg1f_k(const unsigned short* __restrict__ P, const unsigned short* __restrict__ Q,
             const unsigned short* __restrict__ Wt, const unsigned short* __restrict__ tailm_t,
             const int* __restrict__ row_t, const int* __restrict__ col_t,
             unsigned short* __restrict__ out)
{
  int tid = threadIdx.x;
  int e0 = blockIdx.x * 16;
  uint wreg[17];
#pragma unroll
  for (int j = 0; j < 17; ++j) wreg[j] = *(const uint*)(Wt + j * 512 + tid * 2);
  for (int i = 0; i < 16; ++i) {
    int e = e0 + i;
    int r = row_t[e], c = col_t[e];
    uint pv = *(const uint*)(P + ((size_t)r << 9) + tid * 2);
    uint qv = *(const uint*)(Q + ((size_t)c << 9) + tid * 2);
    float s0 = bflo(pv) + bflo(qv);
    float s1 = bfhi(pv) + bfhi(qv);
#pragma unroll
    for (int j = 0; j < 17; ++j) {
      float tj = bf2f(tailm_t[(size_t)e * 24 + j]);
      s0 += tj * bflo(wreg[j]); s1 += tj * bfhi(wreg[j]);
    }
    *(uint*)(out + ((size_t)e << 9) + tid * 2) = packbf(silu_f(s0), silu_f(s1));
  }
}

// ------ w[e,c] = hid[e,:] . cW2t[c,:] (one wave per edge) ------
__global__ __launch_bounds__(256)
void wv_k(const unsigned short* __restrict__ hid, const float* __restrict__ cW2t,
          float* __restrict__ w)
{
  int gid = blockIdx.x * 256 + threadIdx.x;
  int wv = gid >> 6, lane = threadIdx.x & 63;
  short8v hv = *(const short8v*)(hid + ((size_t)wv << 9) + lane * 8);
  float hf[8];
#pragma unroll
  for (int j = 0; j < 8; ++j) hf[j] = bf2f((unsigned short)hv[j]);
  float p[4];
#pragma unroll
  for (int c = 0; c < 4; ++c) {
    const float4* wp = (const float4*)(cW2t + ((size_t)c << 9) + lane * 8);
    float4 w0 = wp[0], w1 = wp[1];
    p[c] = hf[0]*w0.x + hf[1]*w0.y + hf[2]*w0.z + hf[3]*w0.w
         + hf[4]*w1.x + hf[5]*w1.y + hf[6]*w1.z + hf[7]*w1.w;
  }
#pragma unroll
  for (int c = 0; c < 4; ++c) p[c] = wave_sum(p[c]);
  if (lane == 0) {
    float4 o; o.x = p[0]; o.y = p[1]; o.z = p[2]; o.w = p[3];
    *(float4*)(w + (size_t)wv * 4) = o;
  }
}

// ---------------- trans scatter: sumv += cd*w ----------------
__global__ __launch_bounds__(256)
void trsc_k(const float* __restrict__ cd_t, const float* __restrict__ w,
            const int* __restrict__ row_t, float* __restrict__ sumv)
{
  int e = blockIdx.x * 256 + threadIdx.x;          // < EE
  int r = row_t[e];
  float4 wvv = *(const float4*)(w + (size_t)e * 4);
  float wa[4] = {wvv.x, wvv.y, wvv.z, wvv.w};
#pragma unroll
  for (int ci = 0; ci < 4; ++ci)
#pragma unroll
    for (int a = 0; a < 3; ++a)
      atomicAdd(&sumv[r * 12 + ci * 3 + a], cd_t[(size_t)e * 12 + ci * 3 + a] * wa[ci]);
}

__global__ __launch_bounds__(256)
void xnew_k(const float* __restrict__ coord, const float* __restrict__ sumv,
            const int* __restrict__ deg, float* __restrict__ xout)
{
  int id = blockIdx.x * 256 + threadIdx.x;         // < NN*12
  int n = id / 12;
  int cv = 0;
#pragma unroll
  for (int t = 0; t < 8; ++t) cv += deg[(t << 13) + n];
  xout[id] = coord[id] + sumv[id] / fmaxf((float)cv, 1.f);
}

// ------ batched m output: wave per edge over all T*E ------
__global__ __launch_bounds__(256)
void mout_k(const unsigned short* __restrict__ G, const unsigned short* __restrict__ Gc,
            const float* __restrict__ eW2, const float* __restrict__ wea,
            const float* __restrict__ eb2, const float* __restrict__ ea,
            const int* __restrict__ eidx, float* __restrict__ out_m)
{
  int wid = blockIdx.x * 4 + (threadIdx.x >> 6);   // < TE
  int lane = threadIdx.x & 63;
  int t = wid >> 15, le = wid & (EE - 1);
  int r = eidx[(t << 16) + le], c = eidx[(t << 16) + EE + le];
  float eav = ea[wid];
  short8v gv  = *(const short8v*)(G  + ((size_t)r << 9) + lane * 8);
  short8v gcv = *(const short8v*)(Gc + ((size_t)c << 9) + lane * 8);
  const float4* w4 = (const float4*)(eW2 + lane * 8);
  const float4* a4 = (const float4*)(wea + lane * 8);
  float4 w0 = w4[0], w1 = w4[1], a0 = a4[0], a1 = a4[1];
  float wv8[8] = {w0.x,w0.y,w0.z,w0.w,w1.x,w1.y,w1.z,w1.w};
  float av8[8] = {a0.x,a0.y,a0.z,a0.w,a1.x,a1.y,a1.z,a1.w};
  float s = 0.f;
#pragma unroll
  for (int j = 0; j < 8; ++j)
    s += wv8[j] * silu_f(bf2f((unsigned short)gv[j]) + bf2f((unsigned short)gcv[j]) + eav * av8[j]);
  s = wave_sum(s);
  if (lane == 0) out_m[wid] = s + eb2[0];
}

// ---------------- launch ----------------
extern "C" void kernel_launch(void* const* d_in, const int* in_sizes, int n_in,
                              void* d_out, int out_size, void* d_ws, size_t ws_size,
                              hipStream_t stream)
{
  const float* h     = (const float*)d_in[0];
  const float* coord = (const float*)d_in[1];
  const float* ea    = (const float*)d_in[2];
  const int*   eidx  = (const int*)  d_in[3];
  const float* mW1   = (const float*)d_in[4];
  const float* mb1   = (const float*)d_in[5];
  const float* mW2   = (const float*)d_in[6];
  const float* mb2   = (const float*)d_in[7];
  const float* nW1   = (const float*)d_in[8];
  const float* nb1   = (const float*)d_in[9];
  const float* nW2   = (const float*)d_in[10];
  const float* nb2   = (const float*)d_in[11];
  const float* eW1   = (const float*)d_in[12];
  const float* eb1   = (const float*)d_in[13];
  const float* eW2   = (const float*)d_in[14];
  const float* eb2   = (const float*)d_in[15];
  const float* relW  = (const float*)d_in[16];
  const float* cW1   = (const float*)d_in[17];
  const float* cb1   = (const float*)d_in[18];
  const float* cW2   = (const float*)d_in[19];

  float* out   = (float*)d_out;
  float* out_h = out;
  float* out_x = out + (size_t)NN * DD;
  float* out_m = out_x + (size_t)NN * CC * 3;

  char* ws = (char*)d_ws;
  size_t off = 0;
  auto alloc = [&](size_t bytes) -> void* {
    void* p = ws + off; off += (bytes + 255) & ~(size_t)255; return p;
  };
  unsigned short* bufA  = (unsigned short*)alloc((size_t)EE * 512 * 2);   // 32 MB (aliases radial early)
  unsigned short* bufB  = (unsigned short*)alloc((size_t)EE * 512 * 2);   // 32 MB
  float* cd     = (float*)alloc((size_t)TE * 12 * 4);                     // 12.6 MB
  unsigned short* tailm = (unsigned short*)alloc((size_t)TE * 24 * 2);    // 12.6 MB
  unsigned short* segtb = (unsigned short*)alloc((size_t)NN * 512 * 2);   // 8.4 MB
  float* agg    = (float*)alloc((size_t)NN * 512 * 4);                    // 16.8 MB
  unsigned short* aggb  = (unsigned short*)alloc((size_t)NN * 512 * 2);
  unsigned short* h_bf  = (unsigned short*)alloc((size_t)NN * 512 * 2);
  unsigned short* hn_bf = (unsigned short*)alloc((size_t)NN * 512 * 2);
  unsigned short* Pb    = (unsigned short*)alloc((size_t)NN * 512 * 2);
  unsigned short* Qb    = (unsigned short*)alloc((size_t)NN * 512 * 2);
  unsigned short* Gb    = (unsigned short*)alloc((size_t)NN * 512 * 2);
  unsigned short* Gcb   = (unsigned short*)alloc((size_t)NN * 512 * 2);
  unsigned short* mW1a  = (unsigned short*)alloc((size_t)512 * 512 * 2);
  unsigned short* mW1q  = (unsigned short*)alloc((size_t)512 * 512 * 2);
  unsigned short* mW1t  = (unsigned short*)alloc((size_t)17 * 512 * 2);
  unsigned short* mW2b  = (unsigned short*)alloc((size_t)512 * 512 * 2);
  unsigned short* nW1b  = (unsigned short*)alloc((size_t)512 * 1024 * 2);
  unsigned short* nW2b  = (unsigned short*)alloc((size_t)512 * 512 * 2);
  unsigned short* eW1a  = (unsigned short*)alloc((size_t)512 * 512 * 2);
  unsigned short* eW1c  = (unsigned short*)alloc((size_t)512 * 512 * 2);
  float* weab   = (float*)alloc(512 * 4);
  unsigned short* relWb = (unsigned short*)alloc((size_t)TT * 512 * 512 * 2);
  unsigned short* cW1b  = (unsigned short*)alloc((size_t)TT * 512 * 512 * 2);
  int* deg     = (int*)alloc((size_t)TT * NN * 4);
  int* offb    = (int*)alloc((size_t)TT * NN * 4);
  int* cursor  = (int*)alloc((size_t)TT * NN * 4);
  int* order   = (int*)alloc((size_t)TE * 4);
  float* pnrm  = (float*)alloc((size_t)(TE / 256) * 16 * 4);
  float* nrm   = (float*)alloc((size_t)TT * 16 * 4);
  float* wbuf  = (float*)alloc((size_t)EE * 4 * 4);
  float* sumv  = (float*)alloc((size_t)NN * 12 * 4);
  float* radial = (float*)bufA;   // alias: radial f32 (16.8MB) consumed by tails_k before bufA reuse

  hipMemsetAsync(deg,  0, (size_t)TT * NN * 4, stream);
  hipMemsetAsync(agg,  0, (size_t)NN * 512 * 4, stream);
  hipMemsetAsync(sumv, 0, (size_t)NN * 12 * 4, stream);

  auto cvt = [&](const float* in, unsigned short* o, int n) {
    cvt_k<<<(n + 255) / 256, 256, 0, stream>>>(in, o, n);
  };
  cvt(h,    h_bf,  NN * 512);
  cvt(mW2,  mW2b,  512 * 512);
  cvt(nW1,  nW1b,  512 * 1024);
  cvt(nW2,  nW2b,  512 * 512);
  cvt(relW, relWb, TT * 512 * 512);
  cvt(cW1,  cW1b,  TT * 512 * 512);
  slicew_k<<<1024, 256, 0, stream>>>(mW1, mW1a, 1041, 0);
  slicew_k<<<1024, 256, 0, stream>>>(mW1, mW1q, 1041, 512);
  tailw_k<<<34, 256, 0, stream>>>(mW1, mW1t);
  slicew_k<<<1024, 256, 0, stream>>>(eW1, eW1a, 1025, 0);
  slicew_k<<<1024, 256, 0, stream>>>(eW1, eW1c, 1025, 513);
  weaw_k<<<2, 256, 0, stream>>>(eW1, weab);

  // geometry + sort
  cdrad_k<<<TE / 256, 256, 0, stream>>>(coord, eidx, cd, radial, pnrm);
  nrmred_k<<<1, 128, 0, stream>>>(pnrm, nrm);
  tails_k<<<TE / 256, 256, 0, stream>>>(radial, nrm, ea, tailm);
  hist_k<<<TE / 256, 256, 0, stream>>>(eidx, deg);
  scan_k<<<TT, 256, 0, stream>>>(deg, offb, cursor);
  scat_k<<<TE / 256, 256, 0, stream>>>(eidx, cursor, order);

  const dim3 gE(EE / 128, 4), gN(NN / 128, 4);

  // node-level premultiplies: P = h@mW1a^T + mb1 ; Q = h@mW1q^T
  mgemm_k<<<gN, 256, 0, stream>>>(AgDirect{h_bf, 512}, mW1a, 512, mb1, nullptr, nullptr, Pb, 0);
  mgemm_k<<<gN, 256, 0, stream>>>(AgDirect{h_bf, 512}, mW1q, 512, nullptr, nullptr, nullptr, Qb, 0);

  // -------- pass 1: per relation t --------
  for (int t = 0; t < TT; ++t) {
    const int* row_t = eidx + (size_t)t * 2 * EE;
    const int* col_t = row_t + EE;

    msg1f_k<<<EE / 16, 256, 0, stream>>>(Pb, Qb, mW1t,
        tailm + (size_t)t * EE * 24, row_t, col_t, bufA);
    mgemm_k<<<gE, 256, 0, stream>>>(AgDirect{bufA, 512},
        mW2b, 512, mb2, nullptr, nullptr, bufB, FLAG_SILU);

    gsum_k<<<NN, 256, 0, stream>>>(bufB, offb + (t << 13), deg + (t << 13),
        order + (size_t)t * EE, segtb);
    mgemm_k<<<gN, 256, 0, stream>>>(AgDirect{segtb, 512},
        relWb + (size_t)t * 512 * 512, 512, nullptr, agg, agg, nullptr, FLAG_RES);

    mgemm_k<<<gE, 256, 0, stream>>>(AgDirect{bufB, 512},
        cW1b + (size_t)t * 512 * 512, 512, cb1 + (size_t)t * 512, nullptr, nullptr, bufA, FLAG_SILU);
    wv_k<<<(EE * 64) / 256, 256, 0, stream>>>(bufA, cW2 + (size_t)t * 4 * 512, wbuf);
    trsc_k<<<EE / 256, 256, 0, stream>>>(cd + (size_t)t * EE * 12, wbuf, row_t, sumv);
  }

  // -------- node MLP + residual -> h_new --------
  cvt(agg, aggb, NN * 512);
  mgemm_k<<<gN, 256, 0, stream>>>(AgHcat{h_bf, aggb},
      nW1b, 1024, nb1, nullptr, nullptr, bufA, FLAG_SILU);
  mgemm_k<<<gN, 256, 0, stream>>>(AgDirect{bufA, 512},
      nW2b, 512, nb2, h, out_h, hn_bf, FLAG_RES);
  xnew_k<<<(NN * 12) / 256, 256, 0, stream>>>(coord, sumv, deg, out_x);

  // -------- pass 2: G = hn@eW1a^T + eb1 ; Gc = hn@eW1c^T ; fused m --------
  mgemm_k<<<gN, 256, 0, stream>>>(AgDirect{hn_bf, 512}, eW1a, 512, eb1, nullptr, nullptr, Gb, 0);
  mgemm_k<<<gN, 256, 0, stream>>>(AgDirect{hn_bf, 512}, eW1c, 512, nullptr, nullptr, nullptr, Gcb, 0);
  mout_k<<<TE / 4, 256, 0, stream>>>(Gb, Gcb, eW2, weab, eb2, ea, eidx, out_m);

  (void)in_sizes; (void)n_in; (void)out_size; (void)ws_size;
}

// Round 5
// 1872.978 us; speedup vs baseline: 17.7348x; 1.1915x over previous
//
#include <hip/hip_runtime.h>
#include <cstdint>

#define NN 8192
#define DD 512
#define CC 4
#define TT 8
#define EE 32768
#define TE (TT*EE)

typedef __attribute__((ext_vector_type(8))) short short8v;
typedef __attribute__((ext_vector_type(4))) float f32x4;
typedef unsigned int uint;

constexpr int FLAG_SILU = 1, FLAG_RES = 2, FLAG_WEPI = 4;

__device__ __forceinline__ float silu_f(float x) { return x / (1.f + __expf(-x)); }

__device__ __forceinline__ unsigned short f2bf(float f) {
  uint u = __builtin_bit_cast(uint, f);
  u += 0x7fffu + ((u >> 16) & 1u);
  return (unsigned short)(u >> 16);
}
__device__ __forceinline__ float bf2f(unsigned short b) {
  uint u = ((uint)b) << 16;
  return __builtin_bit_cast(float, u);
}
__device__ __forceinline__ float bflo(uint u) { return __builtin_bit_cast(float, u << 16); }
__device__ __forceinline__ float bfhi(uint u) { return __builtin_bit_cast(float, u & 0xffff0000u); }
__device__ __forceinline__ uint packbf(float a, float b) {
  return (uint)f2bf(a) | ((uint)f2bf(b) << 16);
}

__device__ __forceinline__ float wave_sum(float v) {
#pragma unroll
  for (int off = 32; off; off >>= 1) v += __shfl_xor(v, off);
  return v;
}

__device__ __forceinline__ void gload16(const void* g, void* l) {
  __builtin_amdgcn_global_load_lds(
      (const __attribute__((address_space(1))) void*)g,
      (__attribute__((address_space(3))) void*)l, 16, 0, 0);
}

// ---------------- A/B-side gather functors (ptr to 16B-aligned 8-elem chunk) ----------------
struct AgDirect { const unsigned short* p; int K;
  __device__ const void* ptr(int m, int k) const { return p + (size_t)m * K + k; } };

struct AgHcat { const unsigned short* hb; const unsigned short* ab;
  __device__ const void* ptr(int m, int k) const {
    return (k < 512) ? (const void*)(hb + ((size_t)m << 9) + k)
                     : (const void*)(ab + ((size_t)m << 9) + (k - 512)); } };

struct AgSegAll { const unsigned short* seg;   // [T][N][512], k = t*512+hh
  __device__ const void* ptr(int m, int k) const {
    return seg + (((size_t)(k >> 9) * NN + m) << 9) + (k & 511); } };

struct BgDirect { const unsigned short* p; int K;
  __device__ const void* ptr(int o, int k) const { return p + (size_t)o * K + k; } };

struct BgRel { const unsigned short* w;        // [T][D][H], o=d, k=t*512+hh
  __device__ const void* ptr(int o, int k) const {
    return w + (((size_t)(k >> 9) * 512 + o) << 9) + (k & 511); } };

// ------- bf16 MFMA GEMM: out[m][o] = act(A[m,:].W[o,:] + b[o]) (+res | w-epilogue). O = 512 -------
template<class AG, class BG>
__global__ __launch_bounds__(256)
void mgemm_k(AG ag, BG bg, int K,
             const float* __restrict__ bias, const float* __restrict__ res,
             float* __restrict__ outF, unsigned short* __restrict__ outB, int flags,
             const float* __restrict__ cw2, float* __restrict__ wpart)
{
  __shared__ __align__(16) unsigned short As[128 * 64];
  __shared__ __align__(16) unsigned short Bs[128 * 64];
  const int m0 = blockIdx.x * 128, o0 = blockIdx.y * 128;
  const int tid = threadIdx.x, wave = tid >> 6, lane = tid & 63;
  const int wr = (wave >> 1) * 64, wc = (wave & 1) * 64;
  const int rs = lane >> 3, sl = lane & 7;

  f32x4 acc[4][4];
#pragma unroll
  for (int i = 0; i < 4; ++i)
#pragma unroll
    for (int j = 0; j < 4; ++j) acc[i][j] = (f32x4)0.f;

  for (int k0 = 0; k0 < K; k0 += 64) {
#pragma unroll
    for (int i = 0; i < 4; ++i) {
      int r = i * 32 + wave * 8 + rs;
      int slot = sl ^ (r & 7);
      gload16(ag.ptr(m0 + r, k0 + slot * 8), &As[(i * 32 + wave * 8) * 64]);
    }
#pragma unroll
    for (int i = 0; i < 4; ++i) {
      int r = i * 32 + wave * 8 + rs;
      int slot = sl ^ (r & 7);
      gload16(bg.ptr(o0 + r, k0 + slot * 8), &Bs[(i * 32 + wave * 8) * 64]);
    }
    __syncthreads();

    short8v a[4][2], b[4][2];
#pragma unroll
    for (int mi = 0; mi < 4; ++mi)
#pragma unroll
      for (int s = 0; s < 2; ++s) {
        int row = wr + mi * 16 + (lane & 15);
        int slot = (s * 4 + (lane >> 4)) ^ (row & 7);
        a[mi][s] = *(const short8v*)&As[row * 64 + slot * 8];
      }
#pragma unroll
    for (int ni = 0; ni < 4; ++ni)
#pragma unroll
      for (int s = 0; s < 2; ++s) {
        int row = wc + ni * 16 + (lane & 15);
        int slot = (s * 4 + (lane >> 4)) ^ (row & 7);
        b[ni][s] = *(const short8v*)&Bs[row * 64 + slot * 8];
      }
#pragma unroll
    for (int s = 0; s < 2; ++s)
#pragma unroll
      for (int mi = 0; mi < 4; ++mi)
#pragma unroll
        for (int ni = 0; ni < 4; ++ni)
          acc[mi][ni] = __builtin_amdgcn_mfma_f32_16x16x32_bf16(a[mi][s], b[ni][s], acc[mi][ni], 0, 0, 0);
    __syncthreads();
  }

  const int r4 = (lane >> 4) * 4, cl = lane & 15;
  if (flags & FLAG_WEPI) {
    // w[e][c] partial = sum_{cols of this block} silu(v+bias) * cw2[c][col], 8 slices
    const int slice = blockIdx.y * 2 + (wave & 1);
#pragma unroll
    for (int mi = 0; mi < 4; ++mi) {
      float sc[4][4];
#pragma unroll
      for (int rg = 0; rg < 4; ++rg)
#pragma unroll
        for (int c = 0; c < 4; ++c) sc[rg][c] = 0.f;
#pragma unroll
      for (int ni = 0; ni < 4; ++ni) {
        int col = o0 + wc + ni * 16 + cl;
        float c0 = cw2[col], c1 = cw2[512 + col], c2 = cw2[1024 + col], c3 = cw2[1536 + col];
#pragma unroll
        for (int rg = 0; rg < 4; ++rg) {
          float v = silu_f(acc[mi][ni][rg] + bias[col]);
          sc[rg][0] += v * c0; sc[rg][1] += v * c1; sc[rg][2] += v * c2; sc[rg][3] += v * c3;
        }
      }
#pragma unroll
      for (int rg = 0; rg < 4; ++rg)
#pragma unroll
        for (int c = 0; c < 4; ++c) {
          float s = sc[rg][c];
          s += __shfl_xor(s, 1); s += __shfl_xor(s, 2);
          s += __shfl_xor(s, 4); s += __shfl_xor(s, 8);
          sc[rg][c] = s;
        }
      if (cl == 0) {
        int rowLoc = m0 + wr + mi * 16 + r4;
#pragma unroll
        for (int rg = 0; rg < 4; ++rg) {
          float4 o = make_float4(sc[rg][0], sc[rg][1], sc[rg][2], sc[rg][3]);
          *(float4*)&wpart[(((size_t)slice * EE) + rowLoc + rg) * 4] = o;
        }
      }
    }
    return;
  }
#pragma unroll
  for (int mi = 0; mi < 4; ++mi)
#pragma unroll
    for (int ni = 0; ni < 4; ++ni)
#pragma unroll
      for (int rg = 0; rg < 4; ++rg) {
        int row = m0 + wr + mi * 16 + r4 + rg;
        int col = o0 + wc + ni * 16 + cl;
        float v = acc[mi][ni][rg];
        if (bias) v += bias[col];
        if (flags & FLAG_SILU) v = silu_f(v);
        if (flags & FLAG_RES) v += res[(size_t)row * 512 + col];
        if (outF) outF[(size_t)row * 512 + col] = v;
        if (outB) outB[(size_t)row * 512 + col] = f2bf(v);
      }
}

// ---------------- prep kernels ----------------
__global__ __launch_bounds__(256)
void cvt_k(const float* __restrict__ in, unsigned short* __restrict__ out, int n) {
  int i = blockIdx.x * 256 + threadIdx.x;
  if (i < n) out[i] = f2bf(in[i]);
}

__global__ __launch_bounds__(256)
void slicew_k(const float* __restrict__ w, unsigned short* __restrict__ o, int Kin, int col0) {
  int i = blockIdx.x * 256 + threadIdx.x;   // < 512*512
  int r = i >> 9, k = i & 511;
  o[i] = f2bf(w[(size_t)r * Kin + col0 + k]);
}

__global__ __launch_bounds__(256)
void tailw_k(const float* __restrict__ mW1, unsigned short* __restrict__ o) {
  int i = blockIdx.x * 256 + threadIdx.x;   // < 17*512
  if (i >= 17 * 512) return;
  int j = i >> 9, c = i & 511;
  o[i] = f2bf(mW1[(size_t)c * 1041 + 1024 + j]);
}

__global__ __launch_bounds__(256)
void weaw_k(const float* __restrict__ eW1, float* __restrict__ wea) {
  int i = blockIdx.x * 256 + threadIdx.x;   // < 512
  if (i < 512) wea[i] = eW1[(size_t)i * 1025 + 512];
}

// ---------------- counting sort of edges by destination node ----------------
__global__ __launch_bounds__(256)
void hist_k(const int* __restrict__ eidx, int* __restrict__ deg) {
  int id = blockIdx.x * 256 + threadIdx.x;         // < TE
  int t = id >> 15, e = id & (EE - 1);
  atomicAdd(&deg[(t << 13) + eidx[(t << 16) + e]], 1);
}

__global__ __launch_bounds__(256)
void scan_k(const int* __restrict__ deg, int* __restrict__ off, int* __restrict__ cursor) {
  int t = blockIdx.x, tid = threadIdx.x;
  __shared__ int lds[256];
  int base = 0;
  for (int ch = 0; ch < 32; ++ch) {
    int i = ch * 256 + tid;
    int v = deg[(t << 13) + i];
    __syncthreads();
    lds[tid] = v;
    __syncthreads();
    for (int s = 1; s < 256; s <<= 1) {
      int x = (tid >= s) ? lds[tid - s] : 0;
      __syncthreads();
      if (tid >= s) lds[tid] += x;
      __syncthreads();
    }
    int excl = base + lds[tid] - v;
    off[(t << 13) + i] = excl;
    cursor[(t << 13) + i] = excl;
    base += lds[255];
  }
}

__global__ __launch_bounds__(256)
void scat_k(const int* __restrict__ eidx, const float* __restrict__ ea, int* __restrict__ cursor,
            int* __restrict__ order, int* __restrict__ rank,
            int* __restrict__ rowS, int* __restrict__ colS, float* __restrict__ eaS) {
  int id = blockIdx.x * 256 + threadIdx.x;         // < TE
  int t = id >> 15, e = id & (EE - 1);
  int r = eidx[(t << 16) + e], c = eidx[(t << 16) + EE + e];
  int pos = atomicAdd(&cursor[(t << 13) + r], 1);
  size_t g = ((size_t)t << 15) + pos;
  order[g] = e; rank[id] = pos; rowS[g] = r; colS[g] = c; eaS[g] = ea[id];
}

// ---------------- cd / radial at SORTED positions + per-block sq partials ----------------
__global__ __launch_bounds__(256)
void cdrad_k(const float* __restrict__ coord, const int* __restrict__ eidx,
             const int* __restrict__ rank,
             float* __restrict__ cd, float* __restrict__ radial, float* __restrict__ pnrm)
{
  int m = blockIdx.x * 256 + threadIdx.x;          // < TE (original order)
  int t = m >> 15, e = m & (EE - 1);
  int r = eidx[(t << 16) + e], c = eidx[(t << 16) + EE + e];
  size_t s = ((size_t)t << 15) + rank[m];          // sorted pos
  const float4* cv4 = (const float4*)coord;
  float4 A0 = cv4[r * 3], A1 = cv4[r * 3 + 1], A2 = cv4[r * 3 + 2];
  float4 B0 = cv4[c * 3], B1 = cv4[c * 3 + 1], B2 = cv4[c * 3 + 2];
  float d[12] = {A0.x-B0.x, A0.y-B0.y, A0.z-B0.z, A0.w-B0.w,
                 A1.x-B1.x, A1.y-B1.y, A1.z-B1.z, A1.w-B1.w,
                 A2.x-B2.x, A2.y-B2.y, A2.z-B2.z, A2.w-B2.w};
  float4* cdv = (float4*)cd;
  cdv[s*3+0] = make_float4(d[0],d[1],d[2],d[3]);
  cdv[s*3+1] = make_float4(d[4],d[5],d[6],d[7]);
  cdv[s*3+2] = make_float4(d[8],d[9],d[10],d[11]);
  float rad[16], sq[16];
#pragma unroll
  for (int ci = 0; ci < 4; ++ci)
#pragma unroll
    for (int di = 0; di < 4; ++di) {
      float v = d[ci*3]*d[di*3] + d[ci*3+1]*d[di*3+1] + d[ci*3+2]*d[di*3+2];
      rad[ci*4+di] = v; sq[ci*4+di] = v * v;
    }
  float4* rv = (float4*)radial;
#pragma unroll
  for (int i = 0; i < 4; ++i)
    rv[s*4+i] = make_float4(rad[i*4], rad[i*4+1], rad[i*4+2], rad[i*4+3]);
#pragma unroll
  for (int i = 0; i < 16; ++i) sq[i] = wave_sum(sq[i]);
  __shared__ float red[4][16];
  int wv = threadIdx.x >> 6, lane = threadIdx.x & 63;
  if (lane == 0) {
#pragma unroll
    for (int i = 0; i < 16; ++i) red[wv][i] = sq[i];
  }
  __syncthreads();
  if (threadIdx.x < 16)
    pnrm[blockIdx.x * 16 + threadIdx.x] =
        red[0][threadIdx.x] + red[1][threadIdx.x] + red[2][threadIdx.x] + red[3][threadIdx.x];
}

__global__ __launch_bounds__(128)
void nrmred_k(const float* __restrict__ pnrm, float* __restrict__ nrm) {
  int t = threadIdx.x >> 4, j = threadIdx.x & 15;
  float s = 0.f;
  for (int b = 0; b < 128; ++b) s += pnrm[((t * 128 + b) << 4) + j];
  nrm[(t << 4) + j] = s;
}

// tail row (24): rad_norm(16)|ea|0*7  — all in sorted space
__global__ __launch_bounds__(256)
void tails_k(const float* __restrict__ radial, const float* __restrict__ nrm,
             const float* __restrict__ eaS, unsigned short* __restrict__ tailm)
{
  int m = blockIdx.x * 256 + threadIdx.x;          // < TE sorted
  int t = m >> 15;
  unsigned short tmp[24];
#pragma unroll
  for (int j = 0; j < 16; ++j) {
    float r = radial[(size_t)m * 16 + j] / fmaxf(sqrtf(nrm[(t << 4) + j]), 1e-12f);
    tmp[j] = f2bf(r);
  }
  tmp[16] = f2bf(eaS[m]);
#pragma unroll
  for (int j = 17; j < 24; ++j) tmp[j] = 0;
  uint4* dst = (uint4*)(tailm + (size_t)m * 24);
  dst[0] = ((const uint4*)tmp)[0];
  dst[1] = ((const uint4*)tmp)[1];
  dst[2] = ((const uint4*)tmp)[2];
}

// ---------------- fused msg1 (sorted): silu(P[row]+Q[col]+tail.Wt) ----------------
__global__ __launch_bounds__(256)
void msg1f_k(const unsigned short* __restrict__ P, const unsigned short* __restrict__ Q,
             const unsigned short* __restrict__ Wt, const unsigned short* __restrict__ tailm_t,
             const int* __restrict__ rowS_t, const int* __restrict__ colS_t,
             unsigned short* __restrict__ out)
{
  int tid = threadIdx.x;
  int e0 = blockIdx.x * 16;
  uint wreg[17];
#pragma unroll
  for (int j = 0; j < 17; ++j) wreg[j] = *(const uint*)(Wt + j * 512 + tid * 2);
  for (int i = 0; i < 16; ++i) {
    int p = e0 + i;
    int r = rowS_t[p], c = colS_t[p];
    uint pv = *(const uint*)(P + ((size_t)r << 9) + tid * 2);
    uint qv = *(const uint*)(Q + ((size_t)c << 9) + tid * 2);
    float s0 = bflo(pv) + bflo(qv);
    float s1 = bfhi(pv) + bfhi(qv);
#pragma unroll
    for (int j = 0; j < 17; ++j) {
      float tj = bf2f(tailm_t[(size_t)p * 24 + j]);
      s0 += tj * bflo(wreg[j]); s1 += tj * bfhi(wreg[j]);
    }
    *(uint*)(out + ((size_t)p << 9) + tid * 2) = packbf(silu_f(s0), silu_f(s1));
  }
}

// gather-sum (sorted, sequential): seg[n] = sum msg rows [off..off+deg)
__global__ __launch_bounds__(256)
void gsum_k(const unsigned short* __restrict__ msg, const int* __restrict__ off_t,
            const int* __restrict__ deg_t, unsigned short* __restrict__ segt)
{
  int n = blockIdx.x, tid = threadIdx.x;
  int start = off_t[n], d = deg_t[n];
  float s0 = 0.f, s1 = 0.f;
  for (int j = 0; j < d; ++j) {
    uint v = *(const uint*)(msg + ((size_t)(start + j) << 9) + tid * 2);
    s0 += bflo(v); s1 += bfhi(v);
  }
  *(uint*)(segt + ((size_t)n << 9) + tid * 2) = packbf(s0, s1);
}

// ---------------- trans scatter: w = sum 8 slices of wpart; sumv += cd*w ----------------
__global__ __launch_bounds__(256)
void trsc_k(const float* __restrict__ cd_t, const float* __restrict__ wpart,
            const int* __restrict__ rowS_t, float* __restrict__ sumv)
{
  int p = blockIdx.x * 256 + threadIdx.x;          // < EE sorted
  int r = rowS_t[p];
  float w0 = 0.f, w1 = 0.f, w2 = 0.f, w3 = 0.f;
#pragma unroll
  for (int s = 0; s < 8; ++s) {
    float4 v = *(const float4*)&wpart[(((size_t)s * EE) + p) * 4];
    w0 += v.x; w1 += v.y; w2 += v.z; w3 += v.w;
  }
  float wa[4] = {w0, w1, w2, w3};
#pragma unroll
  for (int ci = 0; ci < 4; ++ci)
#pragma unroll
    for (int a = 0; a < 3; ++a)
      atomicAdd(&sumv[r * 12 + ci * 3 + a], cd_t[(size_t)p * 12 + ci * 3 + a] * wa[ci]);
}

__global__ __launch_bounds__(256)
void xnew_k(const float* __restrict__ coord, const float* __restrict__ sumv,
            const int* __restrict__ deg, float* __restrict__ xout)
{
  int id = blockIdx.x * 256 + threadIdx.x;         // < NN*12
  int n = id / 12;
  int cv = 0;
#pragma unroll
  for (int t = 0; t < 8; ++t) cv += deg[(t << 13) + n];
  xout[id] = coord[id] + sumv[id] / fmaxf((float)cv, 1.f);
}

// ------ batched m output (sorted): wave per sorted pos over all T*E ------
__global__ __launch_bounds__(256)
void mout_k(const unsigned short* __restrict__ G, const unsigned short* __restrict__ Gc,
            const float* __restrict__ eW2, const float* __restrict__ wea,
            const float* __restrict__ eb2, const float* __restrict__ eaS,
            const int* __restrict__ rowS, const int* __restrict__ colS,
            const int* __restrict__ order, float* __restrict__ out_m)
{
  int wid = blockIdx.x * 4 + (threadIdx.x >> 6);   // < TE sorted
  int lane = threadIdx.x & 63;
  int t = wid >> 15;
  int r = rowS[wid], c = colS[wid];
  float eav = eaS[wid];
  short8v gv  = *(const short8v*)(G  + ((size_t)r << 9) + lane * 8);
  short8v gcv = *(const short8v*)(Gc + ((size_t)c << 9) + lane * 8);
  const float4* w4 = (const float4*)(eW2 + lane * 8);
  const float4* a4 = (const float4*)(wea + lane * 8);
  float4 w0 = w4[0], w1 = w4[1], a0 = a4[0], a1 = a4[1];
  float wv8[8] = {w0.x,w0.y,w0.z,w0.w,w1.x,w1.y,w1.z,w1.w};
  float av8[8] = {a0.x,a0.y,a0.z,a0.w,a1.x,a1.y,a1.z,a1.w};
  float s = 0.f;
#pragma unroll
  for (int j = 0; j < 8; ++j)
    s += wv8[j] * silu_f(bf2f((unsigned short)gv[j]) + bf2f((unsigned short)gcv[j]) + eav * av8[j]);
  s = wave_sum(s);
  if (lane == 0) out_m[((size_t)t << 15) + order[wid]] = s + eb2[0];
}

// ---------------- launch ----------------
extern "C" void kernel_launch(void* const* d_in, const int* in_sizes, int n_in,
                              void* d_out, int out_size, void* d_ws, size_t ws_size,
                              hipStream_t stream)
{
  const float* h     = (const float*)d_in[0];
  const float* coord = (const float*)d_in[1];
  const float* ea    = (const float*)d_in[2];
  const int*   eidx  = (const int*)  d_in[3];
  const float* mW1   = (const float*)d_in[4];
  const float* mb1   = (const float*)d_in[5];
  const float* mW2   = (const float*)d_in[6];
  const float* mb2   = (const float*)d_in[7];
  const float* nW1   = (const float*)d_in[8];
  const float* nb1   = (const float*)d_in[9];
  const float* nW2   = (const float*)d_in[10];
  const float* nb2   = (const float*)d_in[11];
  const float* eW1   = (const float*)d_in[12];
  const float* eb1   = (const float*)d_in[13];
  const float* eW2   = (const float*)d_in[14];
  const float* eb2   = (const float*)d_in[15];
  const float* relW  = (const float*)d_in[16];
  const float* cW1   = (const float*)d_in[17];
  const float* cb1   = (const float*)d_in[18];
  const float* cW2   = (const float*)d_in[19];

  float* out   = (float*)d_out;
  float* out_h = out;
  float* out_x = out + (size_t)NN * DD;
  float* out_m = out_x + (size_t)NN * CC * 3;

  char* ws = (char*)d_ws;
  size_t off = 0;
  auto alloc = [&](size_t bytes) -> void* {
    void* p = ws + off; off += (bytes + 255) & ~(size_t)255; return p;
  };
  unsigned short* bufA  = (unsigned short*)alloc((size_t)EE * 512 * 2);   // 32 MB (aliases radial early)
  unsigned short* bufB  = (unsigned short*)alloc((size_t)EE * 512 * 2);   // 32 MB
  float* cd     = (float*)alloc((size_t)TE * 12 * 4);                     // 12.6 MB
  unsigned short* tailm = (unsigned short*)alloc((size_t)TE * 24 * 2);    // 12.6 MB
  unsigned short* segall= (unsigned short*)alloc((size_t)TT * NN * 512 * 2); // 67 MB
  unsigned short* aggb  = (unsigned short*)alloc((size_t)NN * 512 * 2);
  unsigned short* h_bf  = (unsigned short*)alloc((size_t)NN * 512 * 2);
  unsigned short* hn_bf = (unsigned short*)alloc((size_t)NN * 512 * 2);
  unsigned short* Pb    = (unsigned short*)alloc((size_t)NN * 512 * 2);
  unsigned short* Qb    = (unsigned short*)alloc((size_t)NN * 512 * 2);
  unsigned short* Gb    = (unsigned short*)alloc((size_t)NN * 512 * 2);
  unsigned short* Gcb   = (unsigned short*)alloc((size_t)NN * 512 * 2);
  unsigned short* mW1a  = (unsigned short*)alloc((size_t)512 * 512 * 2);
  unsigned short* mW1q  = (unsigned short*)alloc((size_t)512 * 512 * 2);
  unsigned short* mW1t  = (unsigned short*)alloc((size_t)17 * 512 * 2);
  unsigned short* mW2b  = (unsigned short*)alloc((size_t)512 * 512 * 2);
  unsigned short* nW1b  = (unsigned short*)alloc((size_t)512 * 1024 * 2);
  unsigned short* nW2b  = (unsigned short*)alloc((size_t)512 * 512 * 2);
  unsigned short* eW1a  = (unsigned short*)alloc((size_t)512 * 512 * 2);
  unsigned short* eW1c  = (unsigned short*)alloc((size_t)512 * 512 * 2);
  float* weab   = (float*)alloc(512 * 4);
  unsigned short* relWb = (unsigned short*)alloc((size_t)TT * 512 * 512 * 2); // 33.6 MB
  unsigned short* cW1b  = (unsigned short*)alloc((size_t)TT * 512 * 512 * 2); // 33.6 MB
  int* deg     = (int*)alloc((size_t)TT * NN * 4);
  int* offb    = (int*)alloc((size_t)TT * NN * 4);
  int* cursor  = (int*)alloc((size_t)TT * NN * 4);
  int* order   = (int*)alloc((size_t)TE * 4);
  int* rank    = (int*)alloc((size_t)TE * 4);
  int* rowS    = (int*)alloc((size_t)TE * 4);
  int* colS    = (int*)alloc((size_t)TE * 4);
  float* eaS   = (float*)alloc((size_t)TE * 4);
  float* wpart = (float*)alloc((size_t)8 * EE * 4 * 4);                   // 4 MB
  float* pnrm  = (float*)alloc((size_t)(TE / 256) * 16 * 4);
  float* nrm   = (float*)alloc((size_t)TT * 16 * 4);
  float* sumv  = (float*)alloc((size_t)NN * 12 * 4);
  float* radial = (float*)bufA;   // alias (16.8 MB), consumed by tails_k before bufA reuse

  hipMemsetAsync(deg,  0, (size_t)TT * NN * 4, stream);
  hipMemsetAsync(sumv, 0, (size_t)NN * 12 * 4, stream);

  auto cvt = [&](const float* in, unsigned short* o, int n) {
    cvt_k<<<(n + 255) / 256, 256, 0, stream>>>(in, o, n);
  };
  cvt(h,    h_bf,  NN * 512);
  cvt(mW2,  mW2b,  512 * 512);
  cvt(nW1,  nW1b,  512 * 1024);
  cvt(nW2,  nW2b,  512 * 512);
  cvt(relW, relWb, TT * 512 * 512);
  cvt(cW1,  cW1b,  TT * 512 * 512);
  slicew_k<<<1024, 256, 0, stream>>>(mW1, mW1a, 1041, 0);
  slicew_k<<<1024, 256, 0, stream>>>(mW1, mW1q, 1041, 512);
  tailw_k<<<34, 256, 0, stream>>>(mW1, mW1t);
  slicew_k<<<1024, 256, 0, stream>>>(eW1, eW1a, 1025, 0);
  slicew_k<<<1024, 256, 0, stream>>>(eW1, eW1c, 1025, 513);
  weaw_k<<<2, 256, 0, stream>>>(eW1, weab);

  // sort + geometry (sorted space)
  hist_k<<<TE / 256, 256, 0, stream>>>(eidx, deg);
  scan_k<<<TT, 256, 0, stream>>>(deg, offb, cursor);
  scat_k<<<TE / 256, 256, 0, stream>>>(eidx, ea, cursor, order, rank, rowS, colS, eaS);
  cdrad_k<<<TE / 256, 256, 0, stream>>>(coord, eidx, rank, cd, radial, pnrm);
  nrmred_k<<<1, 128, 0, stream>>>(pnrm, nrm);
  tails_k<<<TE / 256, 256, 0, stream>>>(radial, nrm, eaS, tailm);

  const dim3 gE(EE / 128, 4), gN(NN / 128, 4);

  // node-level premultiplies: P = h@mW1a^T + mb1 ; Q = h@mW1q^T
  mgemm_k<<<gN, 256, 0, stream>>>(AgDirect{h_bf, 512}, BgDirect{mW1a, 512}, 512,
      mb1, nullptr, nullptr, Pb, 0, nullptr, nullptr);
  mgemm_k<<<gN, 256, 0, stream>>>(AgDirect{h_bf, 512}, BgDirect{mW1q, 512}, 512,
      nullptr, nullptr, nullptr, Qb, 0, nullptr, nullptr);

  // -------- pass 1: per relation t (all in sorted edge order) --------
  for (int t = 0; t < TT; ++t) {
    const size_t tb = (size_t)t << 15;
    msg1f_k<<<EE / 16, 256, 0, stream>>>(Pb, Qb, mW1t, tailm + tb * 24,
        rowS + tb, colS + tb, bufA);
    mgemm_k<<<gE, 256, 0, stream>>>(AgDirect{bufA, 512}, BgDirect{mW2b, 512}, 512,
        mb2, nullptr, nullptr, bufB, FLAG_SILU, nullptr, nullptr);
    gsum_k<<<NN, 256, 0, stream>>>(bufB, offb + (t << 13), deg + (t << 13),
        segall + (size_t)t * NN * 512);
    mgemm_k<<<gE, 256, 0, stream>>>(AgDirect{bufB, 512},
        BgDirect{cW1b + (size_t)t * 512 * 512, 512}, 512,
        cb1 + (size_t)t * 512, nullptr, nullptr, nullptr, FLAG_SILU | FLAG_WEPI,
        cW2 + (size_t)t * 4 * 512, wpart);
    trsc_k<<<EE / 256, 256, 0, stream>>>(cd + tb * 12, wpart, rowS + tb, sumv);
  }

  // -------- agg = concat_t(seg) @ relW (K=4096, one GEMM) --------
  mgemm_k<<<gN, 256, 0, stream>>>(AgSegAll{segall}, BgRel{relWb}, TT * 512,
      nullptr, nullptr, nullptr, aggb, 0, nullptr, nullptr);

  // -------- node MLP + residual -> h_new --------
  mgemm_k<<<gN, 256, 0, stream>>>(AgHcat{h_bf, aggb}, BgDirect{nW1b, 1024}, 1024,
      nb1, nullptr, nullptr, bufA, FLAG_SILU, nullptr, nullptr);
  mgemm_k<<<gN, 256, 0, stream>>>(AgDirect{bufA, 512}, BgDirect{nW2b, 512}, 512,
      nb2, h, out_h, hn_bf, FLAG_RES, nullptr, nullptr);
  xnew_k<<<(NN * 12) / 256, 256, 0, stream>>>(coord, sumv, deg, out_x);

  // -------- pass 2: G = hn@eW1a^T + eb1 ; Gc = hn@eW1c^T ; fused m (sorted) --------
  mgemm_k<<<gN, 256, 0, stream>>>(AgDirect{hn_bf, 512}, BgDirect{eW1a, 512}, 512,
      eb1, nullptr, nullptr, Gb, 0, nullptr, nullptr);
  mgemm_k<<<gN, 256, 0, stream>>>(AgDirect{hn_bf, 512}, BgDirect{eW1c, 512}, 512,
      nullptr, nullptr, nullptr, Gcb, 0, nullptr, nullptr);
  mout_k<<<TE / 4, 256, 0, stream>>>(Gb, Gcb, eW2, weab, eb2, eaS, rowS, colS, order, out_m);

  (void)in_sizes; (void)n_in; (void)out_size; (void)ws_size;
}

// Round 7
// 1671.398 us; speedup vs baseline: 19.8737x; 1.1206x over previous
//
#include <hip/hip_runtime.h>
#include <cstdint>

#define NN 8192
#define DD 512
#define CC 4
#define TT 8
#define EE 32768
#define TE (TT*EE)

typedef __attribute__((ext_vector_type(8))) short short8v;
typedef __attribute__((ext_vector_type(4))) float f32x4;
typedef unsigned int uint;

constexpr int FLAG_SILU = 1, FLAG_RES = 2, FLAG_WEPI = 4, FLAG_BIAS_T = 8;

__device__ __forceinline__ float silu_f(float x) { return x / (1.f + __expf(-x)); }

__device__ __forceinline__ unsigned short f2bf(float f) {
  uint u = __builtin_bit_cast(uint, f);
  u += 0x7fffu + ((u >> 16) & 1u);
  return (unsigned short)(u >> 16);
}
__device__ __forceinline__ float bf2f(unsigned short b) {
  uint u = ((uint)b) << 16;
  return __builtin_bit_cast(float, u);
}
__device__ __forceinline__ float bflo(uint u) { return __builtin_bit_cast(float, u << 16); }
__device__ __forceinline__ float bfhi(uint u) { return __builtin_bit_cast(float, u & 0xffff0000u); }
__device__ __forceinline__ uint packbf(float a, float b) {
  return (uint)f2bf(a) | ((uint)f2bf(b) << 16);
}

__device__ __forceinline__ float wave_sum(float v) {
#pragma unroll
  for (int off = 32; off; off >>= 1) v += __shfl_xor(v, off);
  return v;
}

__device__ __forceinline__ void gload16(const void* g, void* l) {
  __builtin_amdgcn_global_load_lds(
      (const __attribute__((address_space(1))) void*)g,
      (__attribute__((address_space(3))) void*)l, 16, 0, 0);
}

// ---------------- A/B-side gather functors: ptr(m,k,tt) -> 16B-aligned 8-elem chunk ----------------
struct AgDirect { const unsigned short* p; int K;
  __device__ const void* ptr(int m, int k, int) const { return p + (size_t)m * K + k; } };

struct AgHcat { const unsigned short* hb; const unsigned short* ab;
  __device__ const void* ptr(int m, int k, int) const {
    return (k < 512) ? (const void*)(hb + ((size_t)m << 9) + k)
                     : (const void*)(ab + ((size_t)m << 9) + (k - 512)); } };

struct AgSegAll { const unsigned short* seg;   // [T][N][512], k = t*512+hh
  __device__ const void* ptr(int m, int k, int) const {
    return seg + (((size_t)(k >> 9) * NN + m) << 9) + (k & 511); } };

struct BgDirect { const unsigned short* p; int K;
  __device__ const void* ptr(int o, int k, int) const { return p + (size_t)o * K + k; } };

struct BgRel { const unsigned short* w;        // [T][D][H], o=d, k=t*512+hh
  __device__ const void* ptr(int o, int k, int) const {
    return w + (((size_t)(k >> 9) * 512 + o) << 9) + (k & 511); } };

struct BgPerT { const unsigned short* w;       // [T][512][512], per-t select
  __device__ const void* ptr(int o, int k, int tt) const {
    return w + (((size_t)tt << 18) + ((size_t)o << 9)) + k; } };

// ------- bf16 MFMA GEMM: out[m][o] = act(A[m,:].W[o,:] + b) (+res | w-epilogue) -------
template<class AG, class BG>
__global__ __launch_bounds__(256)
void mgemm_k(AG ag, BG bg, int K, int tbase,
             const float* __restrict__ bias, const float* __restrict__ res,
             float* __restrict__ outF, unsigned short* __restrict__ outB, int ldo, int flags,
             const float* __restrict__ cw2, float* __restrict__ wpart, int wstride)
{
  __shared__ __align__(16) unsigned short As[128 * 64];
  __shared__ __align__(16) unsigned short Bs[128 * 64];
  const int m0 = blockIdx.x * 128, o0 = blockIdx.y * 128;
  const int tt = tbase + (m0 >> 15);
  const int tid = threadIdx.x, wave = tid >> 6, lane = tid & 63;
  const int wr = (wave >> 1) * 64, wc = (wave & 1) * 64;
  const int rs = lane >> 3, sl = lane & 7;

  f32x4 acc[4][4];
#pragma unroll
  for (int i = 0; i < 4; ++i)
#pragma unroll
    for (int j = 0; j < 4; ++j) acc[i][j] = (f32x4)0.f;

  for (int k0 = 0; k0 < K; k0 += 64) {
#pragma unroll
    for (int i = 0; i < 4; ++i) {
      int r = i * 32 + wave * 8 + rs;
      int slot = sl ^ (r & 7);
      gload16(ag.ptr(m0 + r, k0 + slot * 8, tt), &As[(i * 32 + wave * 8) * 64]);
    }
#pragma unroll
    for (int i = 0; i < 4; ++i) {
      int r = i * 32 + wave * 8 + rs;
      int slot = sl ^ (r & 7);
      gload16(bg.ptr(o0 + r, k0 + slot * 8, tt), &Bs[(i * 32 + wave * 8) * 64]);
    }
    __syncthreads();

    short8v a[4][2], b[4][2];
#pragma unroll
    for (int mi = 0; mi < 4; ++mi)
#pragma unroll
      for (int s = 0; s < 2; ++s) {
        int row = wr + mi * 16 + (lane & 15);
        int slot = (s * 4 + (lane >> 4)) ^ (row & 7);
        a[mi][s] = *(const short8v*)&As[row * 64 + slot * 8];
      }
#pragma unroll
    for (int ni = 0; ni < 4; ++ni)
#pragma unroll
      for (int s = 0; s < 2; ++s) {
        int row = wc + ni * 16 + (lane & 15);
        int slot = (s * 4 + (lane >> 4)) ^ (row & 7);
        b[ni][s] = *(const short8v*)&Bs[row * 64 + slot * 8];
      }
#pragma unroll
    for (int s = 0; s < 2; ++s)
#pragma unroll
      for (int mi = 0; mi < 4; ++mi)
#pragma unroll
        for (int ni = 0; ni < 4; ++ni)
          acc[mi][ni] = __builtin_amdgcn_mfma_f32_16x16x32_bf16(a[mi][s], b[ni][s], acc[mi][ni], 0, 0, 0);
    __syncthreads();
  }

  const int r4 = (lane >> 4) * 4, cl = lane & 15;
  if (flags & FLAG_WEPI) {
    const int slice = blockIdx.y * 2 + (wave & 1);
    const float* cw2t = cw2 + tt * 2048;
    const float* bt = bias + tt * 512;
#pragma unroll
    for (int mi = 0; mi < 4; ++mi) {
      float sc[4][4];
#pragma unroll
      for (int rg = 0; rg < 4; ++rg)
#pragma unroll
        for (int c = 0; c < 4; ++c) sc[rg][c] = 0.f;
#pragma unroll
      for (int ni = 0; ni < 4; ++ni) {
        int col = o0 + wc + ni * 16 + cl;
        float c0 = cw2t[col], c1 = cw2t[512 + col], c2 = cw2t[1024 + col], c3 = cw2t[1536 + col];
        float bb = bt[col];
#pragma unroll
        for (int rg = 0; rg < 4; ++rg) {
          float v = silu_f(acc[mi][ni][rg] + bb);
          sc[rg][0] += v * c0; sc[rg][1] += v * c1; sc[rg][2] += v * c2; sc[rg][3] += v * c3;
        }
      }
#pragma unroll
      for (int rg = 0; rg < 4; ++rg)
#pragma unroll
        for (int c = 0; c < 4; ++c) {
          float s = sc[rg][c];
          s += __shfl_xor(s, 1); s += __shfl_xor(s, 2);
          s += __shfl_xor(s, 4); s += __shfl_xor(s, 8);
          sc[rg][c] = s;
        }
      if (cl == 0) {
        int p = m0 + wr + mi * 16 + r4;              // group-local sorted pos
#pragma unroll
        for (int rg = 0; rg < 4; ++rg) {
          float4 o = make_float4(sc[rg][0], sc[rg][1], sc[rg][2], sc[rg][3]);
          *(float4*)&wpart[(((size_t)slice * wstride) + p + rg) * 4] = o;
        }
      }
    }
    return;
  }
#pragma unroll
  for (int mi = 0; mi < 4; ++mi)
#pragma unroll
    for (int ni = 0; ni < 4; ++ni)
#pragma unroll
      for (int rg = 0; rg < 4; ++rg) {
        int row = m0 + wr + mi * 16 + r4 + rg;
        int col = o0 + wc + ni * 16 + cl;
        float v = acc[mi][ni][rg];
        if (bias) v += (flags & FLAG_BIAS_T) ? bias[tt * 512 + col] : bias[col];
        if (flags & FLAG_SILU) v = silu_f(v);
        if (flags & FLAG_RES) v += res[(size_t)row * ldo + col];
        if (outF) outF[(size_t)row * ldo + col] = v;
        if (outB) outB[(size_t)row * ldo + col] = f2bf(v);
      }
}

// ---------------- prep kernels ----------------
__global__ __launch_bounds__(256)
void cvt_k(const float* __restrict__ in, unsigned short* __restrict__ out, int n) {
  int i = blockIdx.x * 256 + threadIdx.x;
  if (i < n) out[i] = f2bf(in[i]);
}

__global__ __launch_bounds__(256)
void slicew_k(const float* __restrict__ w, unsigned short* __restrict__ o, int Kin, int col0) {
  int i = blockIdx.x * 256 + threadIdx.x;   // < 512*512
  int r = i >> 9, k = i & 511;
  o[i] = f2bf(w[(size_t)r * Kin + col0 + k]);
}

__global__ __launch_bounds__(256)
void tailw_k(const float* __restrict__ mW1, unsigned short* __restrict__ o) {
  int i = blockIdx.x * 256 + threadIdx.x;   // < 17*512
  if (i >= 17 * 512) return;
  int j = i >> 9, c = i & 511;
  o[i] = f2bf(mW1[(size_t)c * 1041 + 1024 + j]);
}

__global__ __launch_bounds__(256)
void weaw_k(const float* __restrict__ eW1, float* __restrict__ wea) {
  int i = blockIdx.x * 256 + threadIdx.x;   // < 512
  if (i < 512) wea[i] = eW1[(size_t)i * 1025 + 512];
}

__global__ __launch_bounds__(256)
void biasb_k(const float* __restrict__ mb1, const float* __restrict__ eb1,
             float* __restrict__ pqb, float* __restrict__ ggb) {
  int i = blockIdx.x * 256 + threadIdx.x;   // < 1024
  if (i < 1024) {
    pqb[i] = (i < 512) ? mb1[i] : 0.f;
    ggb[i] = (i < 512) ? eb1[i] : 0.f;
  }
}

// ---------------- counting sort of edges by destination node ----------------
__global__ __launch_bounds__(256)
void hist_k(const int* __restrict__ eidx, int* __restrict__ deg) {
  int id = blockIdx.x * 256 + threadIdx.x;         // < TE
  int t = id >> 15, e = id & (EE - 1);
  atomicAdd(&deg[(t << 13) + eidx[(t << 16) + e]], 1);
}

__global__ __launch_bounds__(256)
void scan_k(const int* __restrict__ deg, int* __restrict__ off, int* __restrict__ cursor) {
  int t = blockIdx.x, tid = threadIdx.x;
  __shared__ int lds[256];
  int base = 0;
  for (int ch = 0; ch < 32; ++ch) {
    int i = ch * 256 + tid;
    int v = deg[(t << 13) + i];
    __syncthreads();
    lds[tid] = v;
    __syncthreads();
    for (int s = 1; s < 256; s <<= 1) {
      int x = (tid >= s) ? lds[tid - s] : 0;
      __syncthreads();
      if (tid >= s) lds[tid] += x;
      __syncthreads();
    }
    int excl = base + lds[tid] - v;
    off[(t << 13) + i] = excl;
    cursor[(t << 13) + i] = excl;
    base += lds[255];
  }
}

__global__ __launch_bounds__(256)
void scat_k(const int* __restrict__ eidx, const float* __restrict__ ea, int* __restrict__ cursor,
            int* __restrict__ order, int* __restrict__ rank,
            int* __restrict__ rowS, int* __restrict__ colS, float* __restrict__ eaS) {
  int id = blockIdx.x * 256 + threadIdx.x;         // < TE
  int t = id >> 15, e = id & (EE - 1);
  int r = eidx[(t << 16) + e], c = eidx[(t << 16) + EE + e];
  int pos = atomicAdd(&cursor[(t << 13) + r], 1);
  size_t g = ((size_t)t << 15) + pos;
  order[g] = e; rank[id] = pos; rowS[g] = r; colS[g] = c; eaS[g] = ea[id];
}

// ---------------- cd / radial at SORTED positions + per-block sq partials ----------------
__global__ __launch_bounds__(256)
void cdrad_k(const float* __restrict__ coord, const int* __restrict__ eidx,
             const int* __restrict__ rank,
             float* __restrict__ cd, float* __restrict__ radial, float* __restrict__ pnrm)
{
  int m = blockIdx.x * 256 + threadIdx.x;          // < TE (original order)
  int t = m >> 15, e = m & (EE - 1);
  int r = eidx[(t << 16) + e], c = eidx[(t << 16) + EE + e];
  size_t s = ((size_t)t << 15) + rank[m];          // sorted pos
  const float4* cv4 = (const float4*)coord;
  float4 A0 = cv4[r * 3], A1 = cv4[r * 3 + 1], A2 = cv4[r * 3 + 2];
  float4 B0 = cv4[c * 3], B1 = cv4[c * 3 + 1], B2 = cv4[c * 3 + 2];
  float d[12] = {A0.x-B0.x, A0.y-B0.y, A0.z-B0.z, A0.w-B0.w,
                 A1.x-B1.x, A1.y-B1.y, A1.z-B1.z, A1.w-B1.w,
                 A2.x-B2.x, A2.y-B2.y, A2.z-B2.z, A2.w-B2.w};
  float4* cdv = (float4*)cd;
  cdv[s*3+0] = make_float4(d[0],d[1],d[2],d[3]);
  cdv[s*3+1] = make_float4(d[4],d[5],d[6],d[7]);
  cdv[s*3+2] = make_float4(d[8],d[9],d[10],d[11]);
  float rad[16], sq[16];
#pragma unroll
  for (int ci = 0; ci < 4; ++ci)
#pragma unroll
    for (int di = 0; di < 4; ++di) {
      float v = d[ci*3]*d[di*3] + d[ci*3+1]*d[di*3+1] + d[ci*3+2]*d[di*3+2];
      rad[ci*4+di] = v; sq[ci*4+di] = v * v;
    }
  float4* rv = (float4*)radial;
#pragma unroll
  for (int i = 0; i < 4; ++i)
    rv[s*4+i] = make_float4(rad[i*4], rad[i*4+1], rad[i*4+2], rad[i*4+3]);
#pragma unroll
  for (int i = 0; i < 16; ++i) sq[i] = wave_sum(sq[i]);
  __shared__ float red[4][16];
  int wv = threadIdx.x >> 6, lane = threadIdx.x & 63;
  if (lane == 0) {
#pragma unroll
    for (int i = 0; i < 16; ++i) red[wv][i] = sq[i];
  }
  __syncthreads();
  if (threadIdx.x < 16)
    pnrm[blockIdx.x * 16 + threadIdx.x] =
        red[0][threadIdx.x] + red[1][threadIdx.x] + red[2][threadIdx.x] + red[3][threadIdx.x];
}

__global__ __launch_bounds__(128)
void nrmred_k(const float* __restrict__ pnrm, float* __restrict__ nrm) {
  int t = threadIdx.x >> 4, j = threadIdx.x & 15;
  float s = 0.f;
  for (int b = 0; b < 128; ++b) s += pnrm[((t * 128 + b) << 4) + j];
  nrm[(t << 4) + j] = s;
}

// tail row (24): rad_norm(16)|ea|0*7  — sorted space
__global__ __launch_bounds__(256)
void tails_k(const float* __restrict__ radial, const float* __restrict__ nrm,
             const float* __restrict__ eaS, unsigned short* __restrict__ tailm)
{
  int m = blockIdx.x * 256 + threadIdx.x;          // < TE sorted
  int t = m >> 15;
  unsigned short tmp[24];
#pragma unroll
  for (int j = 0; j < 16; ++j) {
    float r = radial[(size_t)m * 16 + j] / fmaxf(sqrtf(nrm[(t << 4) + j]), 1e-12f);
    tmp[j] = f2bf(r);
  }
  tmp[16] = f2bf(eaS[m]);
#pragma unroll
  for (int j = 17; j < 24; ++j) tmp[j] = 0;
  uint4* dst = (uint4*)(tailm + (size_t)m * 24);
  dst[0] = ((const uint4*)tmp)[0];
  dst[1] = ((const uint4*)tmp)[1];
  dst[2] = ((const uint4*)tmp)[2];
}

// ---------------- fused msg1 (sorted, batched group): silu(P[row]+Q[col]+tail.Wt) ----------------
__global__ __launch_bounds__(256)
void msg1f_k(const unsigned short* __restrict__ PQ, const unsigned short* __restrict__ Wt,
             const unsigned short* __restrict__ tailm_g,
             const int* __restrict__ rowS_g, const int* __restrict__ colS_g,
             unsigned short* __restrict__ out)
{
  int tid = threadIdx.x;
  int e0 = blockIdx.x * 16;
  uint wreg[17];
#pragma unroll
  for (int j = 0; j < 17; ++j) wreg[j] = *(const uint*)(Wt + j * 512 + tid * 2);
  for (int i = 0; i < 16; ++i) {
    int p = e0 + i;
    int r = rowS_g[p], c = colS_g[p];
    uint pv = *(const uint*)(PQ + ((size_t)r << 10) + tid * 2);
    uint qv = *(const uint*)(PQ + ((size_t)c << 10) + 512 + tid * 2);
    float s0 = bflo(pv) + bflo(qv);
    float s1 = bfhi(pv) + bfhi(qv);
#pragma unroll
    for (int j = 0; j < 17; ++j) {
      float tj = bf2f(tailm_g[(size_t)p * 24 + j]);
      s0 += tj * bflo(wreg[j]); s1 += tj * bfhi(wreg[j]);
    }
    *(uint*)(out + ((size_t)p << 9) + tid * 2) = packbf(silu_f(s0), silu_f(s1));
  }
}

// gather-sum (sorted, sequential, batched group): seg[t][n] = sum msg rows
__global__ __launch_bounds__(256)
void gsum_k(const unsigned short* __restrict__ msg, const int* __restrict__ offb,
            const int* __restrict__ deg, int tbase, unsigned short* __restrict__ segall)
{
  int tloc = blockIdx.x >> 13, n = blockIdx.x & (NN - 1), tid = threadIdx.x;
  int t = tbase + tloc;
  int start = offb[(t << 13) + n], d = deg[(t << 13) + n];
  float s0 = 0.f, s1 = 0.f;
  const unsigned short* base = msg + (((size_t)tloc << 15) << 9);
  for (int j = 0; j < d; ++j) {
    uint v = *(const uint*)(base + ((size_t)(start + j) << 9) + tid * 2);
    s0 += bflo(v); s1 += bfhi(v);
  }
  *(uint*)(segall + (((size_t)t * NN + n) << 9) + tid * 2) = packbf(s0, s1);
}

// ---------------- wsum: collapse 8 group-local wpart slices into global wsumb ----------------
__global__ __launch_bounds__(256)
void wsum_k(const float* __restrict__ wpart, float* __restrict__ wsum_out, int wstride) {
  int id = blockIdx.x * 256 + threadIdx.x;          // < wstride
  float4 a = (float4){0.f, 0.f, 0.f, 0.f};
#pragma unroll
  for (int s = 0; s < 8; ++s) {
    float4 v = *(const float4*)&wpart[(((size_t)s * wstride) + id) * 4];
    a.x += v.x; a.y += v.y; a.z += v.z; a.w += v.w;
  }
  *(float4*)&wsum_out[(size_t)id * 4] = a;
}

// ---------------- fused trans-reduce + x_new (no atomics, CSR walk) ----------------
__global__ __launch_bounds__(256)
void trxn_k(const float* __restrict__ coord, const float* __restrict__ cd,
            const float* __restrict__ wsum, const int* __restrict__ offb,
            const int* __restrict__ deg, float* __restrict__ xout)
{
  int id = blockIdx.x * 256 + threadIdx.x;          // < NN*12
  int n = id / 12, j = id - n * 12, ci = j / 3;
  float s = 0.f; int cnt = 0;
#pragma unroll
  for (int t = 0; t < 8; ++t) {
    int o = offb[(t << 13) + n], d = deg[(t << 13) + n];
    size_t p = ((size_t)t << 15) + o;
    for (int k = 0; k < d; ++k)
      s += cd[(p + k) * 12 + j] * wsum[(p + k) * 4 + ci];
    cnt += d;
  }
  xout[id] = coord[id] + s / fmaxf((float)cnt, 1.f);
}

// ------ batched m output (sorted): wave per sorted pos over all T*E ------
__global__ __launch_bounds__(256)
void mout_k(const unsigned short* __restrict__ GG,
            const float* __restrict__ eW2, const float* __restrict__ wea,
            const float* __restrict__ eb2, const float* __restrict__ eaS,
            const int* __restrict__ rowS, const int* __restrict__ colS,
            const int* __restrict__ order, float* __restrict__ out_m)
{
  int wid = blockIdx.x * 4 + (threadIdx.x >> 6);   // < TE sorted
  int lane = threadIdx.x & 63;
  int t = wid >> 15;
  int r = rowS[wid], c = colS[wid];
  float eav = eaS[wid];
  short8v gv  = *(const short8v*)(GG + ((size_t)r << 10) + lane * 8);
  short8v gcv = *(const short8v*)(GG + ((size_t)c << 10) + 512 + lane * 8);
  const float4* w4 = (const float4*)(eW2 + lane * 8);
  const float4* a4 = (const float4*)(wea + lane * 8);
  float4 w0 = w4[0], w1 = w4[1], a0 = a4[0], a1 = a4[1];
  float wv8[8] = {w0.x,w0.y,w0.z,w0.w,w1.x,w1.y,w1.z,w1.w};
  float av8[8] = {a0.x,a0.y,a0.z,a0.w,a1.x,a1.y,a1.z,a1.w};
  float s = 0.f;
#pragma unroll
  for (int j = 0; j < 8; ++j)
    s += wv8[j] * silu_f(bf2f((unsigned short)gv[j]) + bf2f((unsigned short)gcv[j]) + eav * av8[j]);
  s = wave_sum(s);
  if (lane == 0) out_m[((size_t)t << 15) + order[wid]] = s + eb2[0];
}

// ---------------- launch ----------------
extern "C" void kernel_launch(void* const* d_in, const int* in_sizes, int n_in,
                              void* d_out, int out_size, void* d_ws, size_t ws_size,
                              hipStream_t stream)
{
  const float* h     = (const float*)d_in[0];
  const float* coord = (const float*)d_in[1];
  const float* ea    = (const float*)d_in[2];
  const int*   eidx  = (const int*)  d_in[3];
  const float* mW1   = (const float*)d_in[4];
  const float* mb1   = (const float*)d_in[5];
  const float* mW2   = (const float*)d_in[6];
  const float* mb2   = (const float*)d_in[7];
  const float* nW1   = (const float*)d_in[8];
  const float* nb1   = (const float*)d_in[9];
  const float* nW2   = (const float*)d_in[10];
  const float* nb2   = (const float*)d_in[11];
  const float* eW1   = (const float*)d_in[12];
  const float* eb1   = (const float*)d_in[13];
  const float* eW2   = (const float*)d_in[14];
  const float* eb2   = (const float*)d_in[15];
  const float* relW  = (const float*)d_in[16];
  const float* cW1   = (const float*)d_in[17];
  const float* cb1   = (const float*)d_in[18];
  const float* cW2   = (const float*)d_in[19];

  float* out   = (float*)d_out;
  float* out_h = out;
  float* out_x = out + (size_t)NN * DD;
  float* out_m = out_x + (size_t)NN * CC * 3;

  char* ws = (char*)d_ws;
  size_t off = 0;
  auto alloc = [&](size_t bytes) -> void* {
    void* p = ws + off; off += (bytes + 255) & ~(size_t)255; return p;
  };
  // ---- fixed buffers (~216 MB) ----
  float* cd     = (float*)alloc((size_t)TE * 12 * 4);                     // 12.6 MB
  unsigned short* tailm = (unsigned short*)alloc((size_t)TE * 24 * 2);    // 12.6 MB
  unsigned short* segall= (unsigned short*)alloc((size_t)TT * NN * 512 * 2); // 67 MB
  unsigned short* aggb  = (unsigned short*)alloc((size_t)NN * 512 * 2);
  unsigned short* h_bf  = (unsigned short*)alloc((size_t)NN * 512 * 2);
  unsigned short* hn_bf = (unsigned short*)alloc((size_t)NN * 512 * 2);
  unsigned short* PQb   = (unsigned short*)alloc((size_t)NN * 1024 * 2);  // 16.8 MB (GGb aliases)
  unsigned short* GGb   = PQb;                                            // pass-2 alias (PQ dead)
  unsigned short* mW1pq = (unsigned short*)alloc((size_t)1024 * 512 * 2);
  unsigned short* mW1t  = (unsigned short*)alloc((size_t)17 * 512 * 2);
  unsigned short* mW2b  = (unsigned short*)alloc((size_t)512 * 512 * 2);
  unsigned short* nW1b  = (unsigned short*)alloc((size_t)512 * 1024 * 2);
  unsigned short* nW2b  = (unsigned short*)alloc((size_t)512 * 512 * 2);
  unsigned short* eGc   = (unsigned short*)alloc((size_t)1024 * 512 * 2);
  float* weab   = (float*)alloc(512 * 4);
  float* pqbias = (float*)alloc(1024 * 4);
  float* ggbias = (float*)alloc(1024 * 4);
  unsigned short* relWb = (unsigned short*)alloc((size_t)TT * 512 * 512 * 2); // 33.6 MB
  unsigned short* cW1b  = (unsigned short*)alloc((size_t)TT * 512 * 512 * 2); // 33.6 MB
  int* deg     = (int*)alloc((size_t)TT * NN * 4);
  int* offb    = (int*)alloc((size_t)TT * NN * 4);
  int* cursor  = (int*)alloc((size_t)TT * NN * 4);
  int* order   = (int*)alloc((size_t)TE * 4);
  int* rank    = (int*)alloc((size_t)TE * 4);
  int* rowS    = (int*)alloc((size_t)TE * 4);
  int* colS    = (int*)alloc((size_t)TE * 4);
  float* eaS   = (float*)alloc((size_t)TE * 4);
  float* wsumb = (float*)alloc((size_t)TE * 4 * 4);                       // 4.2 MB
  float* pnrm  = (float*)alloc((size_t)(TE / 256) * 16 * 4);
  float* nrm   = (float*)alloc((size_t)TT * 16 * 4);

  // ---- choose group size G so bufA+bufB+wpart fit: per-G cost = 2*33.55 + 4.19 MB ----
  int G = 4;
  while (G > 1) {
    size_t need = off + (size_t)2 * G * EE * 512 * 2 + (size_t)8 * G * EE * 16 + (1 << 20);
    if (need <= ws_size) break;
    G >>= 1;
  }
  unsigned short* bufA = (unsigned short*)alloc((size_t)G * EE * 512 * 2);
  unsigned short* bufB = (unsigned short*)alloc((size_t)G * EE * 512 * 2);
  float* wpart = (float*)alloc((size_t)8 * G * EE * 4 * 4);               // group-local
  float* radial = (float*)bufA;   // alias: radial f32 (16.8 MB) consumed by tails_k before bufA use

  hipMemsetAsync(deg, 0, (size_t)TT * NN * 4, stream);

  auto cvt = [&](const float* in, unsigned short* o, int n) {
    cvt_k<<<(n + 255) / 256, 256, 0, stream>>>(in, o, n);
  };
  cvt(h,    h_bf,  NN * 512);
  cvt(mW2,  mW2b,  512 * 512);
  cvt(nW1,  nW1b,  512 * 1024);
  cvt(nW2,  nW2b,  512 * 512);
  cvt(relW, relWb, TT * 512 * 512);
  cvt(cW1,  cW1b,  TT * 512 * 512);
  slicew_k<<<1024, 256, 0, stream>>>(mW1, mW1pq, 1041, 0);
  slicew_k<<<1024, 256, 0, stream>>>(mW1, mW1pq + 512 * 512, 1041, 512);
  tailw_k<<<34, 256, 0, stream>>>(mW1, mW1t);
  slicew_k<<<1024, 256, 0, stream>>>(eW1, eGc, 1025, 0);
  slicew_k<<<1024, 256, 0, stream>>>(eW1, eGc + 512 * 512, 1025, 513);
  weaw_k<<<2, 256, 0, stream>>>(eW1, weab);
  biasb_k<<<4, 256, 0, stream>>>(mb1, eb1, pqbias, ggbias);

  // sort + geometry (sorted space)
  hist_k<<<TE / 256, 256, 0, stream>>>(eidx, deg);
  scan_k<<<TT, 256, 0, stream>>>(deg, offb, cursor);
  scat_k<<<TE / 256, 256, 0, stream>>>(eidx, ea, cursor, order, rank, rowS, colS, eaS);
  cdrad_k<<<TE / 256, 256, 0, stream>>>(coord, eidx, rank, cd, radial, pnrm);
  nrmred_k<<<1, 128, 0, stream>>>(pnrm, nrm);
  tails_k<<<TE / 256, 256, 0, stream>>>(radial, nrm, eaS, tailm);

  const dim3 gN4(NN / 128, 4), gN8(NN / 128, 8);

  // PQ = h @ [mW1a;mW1q]^T + [mb1;0]   (N x 1024)
  mgemm_k<<<gN8, 256, 0, stream>>>(AgDirect{h_bf, 512}, BgDirect{mW1pq, 512}, 512, 0,
      pqbias, nullptr, nullptr, PQb, 1024, 0, nullptr, nullptr, 0);

  // -------- pass 1: batched groups of G relations --------
  for (int g = 0; g < TT / G; ++g) {
    const int tbase = g * G;
    const size_t gb = (size_t)tbase << 15;
    msg1f_k<<<(G * EE) / 16, 256, 0, stream>>>(PQb, mW1t, tailm + gb * 24,
        rowS + gb, colS + gb, bufA);
    mgemm_k<<<dim3(G * EE / 128, 4), 256, 0, stream>>>(AgDirect{bufA, 512},
        BgDirect{mW2b, 512}, 512, tbase,
        mb2, nullptr, nullptr, bufB, 512, FLAG_SILU, nullptr, nullptr, 0);
    gsum_k<<<G * NN, 256, 0, stream>>>(bufB, offb, deg, tbase, segall);
    mgemm_k<<<dim3(G * EE / 128, 4), 256, 0, stream>>>(AgDirect{bufB, 512},
        BgPerT{cW1b}, 512, tbase,
        cb1, nullptr, nullptr, nullptr, 512, FLAG_SILU | FLAG_WEPI | FLAG_BIAS_T,
        cW2, wpart, G * EE);
    wsum_k<<<(G * EE) / 256, 256, 0, stream>>>(wpart, wsumb + gb * 4, G * EE);
  }

  // fused trans-reduce + x_new (no atomics)
  trxn_k<<<(NN * 12) / 256, 256, 0, stream>>>(coord, cd, wsumb, offb, deg, out_x);

  // -------- agg = concat_t(seg) @ relW (K=4096) --------
  mgemm_k<<<gN4, 256, 0, stream>>>(AgSegAll{segall}, BgRel{relWb}, TT * 512, 0,
      nullptr, nullptr, nullptr, aggb, 512, 0, nullptr, nullptr, 0);

  // -------- node MLP + residual -> h_new --------
  mgemm_k<<<gN4, 256, 0, stream>>>(AgHcat{h_bf, aggb}, BgDirect{nW1b, 1024}, 1024, 0,
      nb1, nullptr, nullptr, bufA, 512, FLAG_SILU, nullptr, nullptr, 0);
  mgemm_k<<<gN4, 256, 0, stream>>>(AgDirect{bufA, 512}, BgDirect{nW2b, 512}, 512, 0,
      nb2, h, out_h, hn_bf, 512, FLAG_RES, nullptr, nullptr, 0);

  // -------- pass 2: GG = hn @ [eW1a;eW1c]^T + [eb1;0] ; fused m (sorted) --------
  mgemm_k<<<gN8, 256, 0, stream>>>(AgDirect{hn_bf, 512}, BgDirect{eGc, 512}, 512, 0,
      ggbias, nullptr, nullptr, GGb, 1024, 0, nullptr, nullptr, 0);
  mout_k<<<TE / 4, 256, 0, stream>>>(GGb, eW2, weab, eb2, eaS, rowS, colS, order, out_m);

  (void)in_sizes; (void)n_in; (void)out_size; (void)ws_size;
}